// Round 8
// baseline (305.793 us; speedup 1.0000x reference)
//
#include <hip/hip_runtime.h>
#include <math.h>

// RelativeAttention: out = round((x_n @ a_n^T)/0.05)*0.05 @ values
//
// Round 25 (from r24 @ 285.0us): 32x32x16 MFMA core (was 16x16x32).
// Profile is diffuse (matrix 25%, VALU 22%, LDS ~27%, waits ~25%); five
// schedule variants were null -> shrink per-tile instruction count instead:
// 32 MFMA/wave/K-tile (was 64), 258 vs 310 matrix cyc, IDENTICAL ds_read
// count/bytes (16B/lane frags in both shapes). Same 8-phase skeleton,
// staging, chunk-XOR swizzle, vmcnt(6)@ph4/ph8, setprio.
//  - A/B frag: lane&31 = row, (lane>>5)*8 = k-offset (analogy of working
//    16x16 pattern); C/D: col=lane&31, row=(reg&3)+8(reg>>2)+4(lane>>5)
//    (guide m74/m101, dtype-independent).
//  - ks-chunk address: base ^ (ks*16 shorts) -- XOR valid because the
//    swizzled s-field occupies exactly those bits (no carry).
//  - numerics: reorder deltas ~1e-6 << 2e-3 flag window -> near-boundary
//    cases still flagged and f64-fixed -> kb2 bit-identical (absmax canary
//    2.685547e-3).
//  - fixup: r24 wave-per-flag 2-deep pipeline (proven +6us). Epilogues
//    re-indexed for the 32x32 C/D layout, logic unchanged.
//
// ws layout (bytes):
//   [0x0,       0x24000)   inv_norms f64 (16384 x | 2048 anchors)
//   [0x24000,   0x24200)   counts u32[64] (128 slots reserved)
//   [0x24200,   0x224200)  lists u32[64][8192]
//   [0x324000,  0x2324000) xh f16 [16384][1024] (32MB)
//   [0x2324000, 0x2724000) ah f16 [2048][1024] (4MB)
//   [0x2724000, 0x2B24000) vbT bf16 [1024][2048] (values^T, 4MB)
//   [0x2B24000, 0x6B24000) kb2 bf16 [16384][2048] (2*bin, odd = midpoint)

#define B_ROWS 16384
#define A_ROWS 2048
#define D_DIM  1024
#define H_DIM  1024
#define TILE_CAP 8192u
#define LCAP 2040u

typedef __attribute__((ext_vector_type(8))) short short8;
typedef __attribute__((ext_vector_type(8))) _Float16 half8;
typedef __attribute__((ext_vector_type(16))) float f32x16;

__device__ inline unsigned short bf16_rne(float f) {
  unsigned int u = __float_as_uint(f);
  unsigned int r = (u + 0x7FFFu + ((u >> 16) & 1u)) >> 16;
  return (unsigned short)r;
}
__device__ inline unsigned short f16_bits(float f) {
  _Float16 h = (_Float16)f;
  return __builtin_bit_cast(unsigned short, h);
}
__device__ inline void gload16(const void* g, void* l) {
  __builtin_amdgcn_global_load_lds(
      (const __attribute__((address_space(1))) unsigned int*)g,
      (__attribute__((address_space(3))) unsigned int*)l, 16, 0, 0);
}

template <bool F16>
__device__ __forceinline__ f32x16 mm32(short8 a, short8 b, f32x16 c) {
  if constexpr (F16)
    return __builtin_amdgcn_mfma_f32_32x32x16_f16(
        __builtin_bit_cast(half8, a), __builtin_bit_cast(half8, b), c, 0, 0, 0);
  else
    return __builtin_amdgcn_mfma_f32_32x32x16_bf16(a, b, c, 0, 0, 0);
}

// ------------- fused: norm (f64, r3-proven tree) + f16 convert -------------
__global__ __launch_bounds__(256) void normprep_k(
    const float* __restrict__ src, double* __restrict__ inv_out,
    unsigned short* __restrict__ dst) {
#pragma clang fp contract(off)
  const int r = blockIdx.x;
  const int t = threadIdx.x;
  const float4 v = reinterpret_cast<const float4*>(src + (size_t)r * D_DIM)[t];
  double s = (double)v.x * (double)v.x + (double)v.y * (double)v.y +
             (double)v.z * (double)v.z + (double)v.w * (double)v.w;
#pragma unroll
  for (int off = 32; off > 0; off >>= 1) s += __shfl_down(s, off);
  __shared__ double red[4];
  __shared__ double sinv;
  if ((t & 63) == 0) red[t >> 6] = s;
  __syncthreads();
  if (t == 0) {
    const double n = sqrt(red[0] + red[1] + red[2] + red[3]);
    const double inv = 1.0 / fmax(n, 1e-12);
    inv_out[r] = inv;
    sinv = inv;
  }
  __syncthreads();
  const float invn = (float)sinv;
  ushort4 o;
  o.x = f16_bits(v.x * invn); o.y = f16_bits(v.y * invn);
  o.z = f16_bits(v.z * invn); o.w = f16_bits(v.w * invn);
  reinterpret_cast<ushort4*>(dst + (size_t)r * D_DIM)[t] = o;
}

// ---------------------- prep: values^T as bf16 (+ zero counts) -------------
__global__ void prep_vt_k(const float* __restrict__ values,
                          unsigned short* __restrict__ vbT,
                          unsigned int* __restrict__ counts) {
  __shared__ float s[16][17];
  const int tx = threadIdx.x, ty = threadIdx.y;
  if (blockIdx.x == 0 && blockIdx.y == 0) {
    const int ft = ty * 16 + tx;
    if (ft < 128) counts[ft] = 0;
  }
  const int h0 = blockIdx.x * 16, a0 = blockIdx.y * 16;
  s[ty][tx] = values[(size_t)(a0 + ty) * H_DIM + h0 + tx];
  __syncthreads();
  vbT[(size_t)(h0 + ty) * A_ROWS + a0 + tx] = bf16_rne(s[tx][ty]);
}

// ------ 256x256 / BK=64 / 8-wave / 8-phase 32x32x16 GEMM core -------------
// LDS: buf0 {A:[256][64] @0, B @16384}, buf1 {A @32768, B @49152} (shorts).
// Chunk-XOR swizzle: row r's chunk k (16B) lives at slot k^(r&7); staging
// pre-swizzles the per-lane GLOBAL source so the LDS dest stays linear.
#define GBAR() do { __builtin_amdgcn_s_barrier(); \
                    asm volatile("" ::: "memory"); } while (0)
#define GVMC(n) asm volatile("s_waitcnt vmcnt(" #n ")" ::: "memory")

#define A0OFF 0
#define B0OFF 16384
#define A1OFF 32768
#define B1OFF 49152

#define SCA(boff, c, kv) gload16(aS + (size_t)(c) * 64 * KDIM + (kv), \
                                 smem + (boff) + (c) * 4096 + tid * 8)
#define SCB(boff, c, kv) gload16(bS + (size_t)(c) * 64 * KDIM + (kv), \
                                 smem + (boff) + (c) * 4096 + tid * 8)

// frag reads: plain C++ short8 loads; ks-chunk via XOR on the swizzled
// s-field (bits 4-5 of the short offset) -- no carry, compiler folds consts.
#define LDX(boff, mh) do { \
    _Pragma("unroll") for (int mb_ = 0; mb_ < 2; ++mb_) \
    _Pragma("unroll") for (int ks_ = 0; ks_ < 4; ++ks_) \
      Xf[mb_][ks_] = *reinterpret_cast<const short8*>( \
          smem + (boff) + (mh) * 8192 + mb_ * 2048 + (sAbase ^ (ks_ * 16))); \
  } while (0)

#define LDB(boff, nh) do { \
    _Pragma("unroll") for (int ks_ = 0; ks_ < 4; ++ks_) \
      Bf[nh][ks_] = *reinterpret_cast<const short8*>( \
          smem + (boff) + (nh) * 8192 + (sBbase ^ (ks_ * 16))); \
  } while (0)

#define MM4(mh, nh) do { \
    __builtin_amdgcn_s_setprio(1); \
    _Pragma("unroll") for (int ks_ = 0; ks_ < 4; ++ks_) \
    _Pragma("unroll") for (int mb_ = 0; mb_ < 2; ++mb_) \
      acc[(mh) * 2 + mb_][nh] = mm32<F16>( \
          Xf[mb_][ks_], Bf[nh][ks_], acc[(mh) * 2 + mb_][nh]); \
    __builtin_amdgcn_s_setprio(0); \
  } while (0)

template <int KDIM, bool F16>
__device__ __forceinline__ void gemm_core(
    const unsigned short* __restrict__ Amat, int m0,
    const unsigned short* __restrict__ Bmat, int n0,
    unsigned short* smem, f32x16 (&acc)[4][2], const int tid) {
  static_assert(KDIM % 128 == 0 && KDIM >= 256, "KDIM");
  const int lane = tid & 63, w = tid >> 6;
  const int wr = w >> 2, wc = w & 3;
  // staging geometry: call c covers rows c*64 + (tid>>3), chunk slot tid&7;
  // source chunk = slot ^ (row&7); (c*64)&7==0 so the XOR is c-invariant.
  const int srow = tid >> 3;
  const int tcs = (tid & 7) ^ (srow & 7);
  const unsigned short* aS = Amat + (size_t)(m0 + srow) * KDIM + tcs * 8;
  const unsigned short* bS = Bmat + (size_t)(n0 + srow) * KDIM + tcs * 8;

  // 32x32 frag-read bases (shorts): row = (lane&31) within block; chunk
  // c = (ks*2 + hi) ^ (row&7), hi = lane>>5. base holds hi^(r&1) (bit 3)
  // and s = (r&7)>>1 (bits 4-5); ks XORs bits 4-5.
  const int hi = lane >> 5, l31 = lane & 31;
  const int sfield = (lane & 6) * 8 + ((hi ^ (lane & 1)) * 8);
  const int sAbase = (wr * 64 + l31) * 64 + sfield;
  const int sBbase = (wc * 32 + l31) * 64 + sfield;

  short8 Xf[2][4], Bf[2][4];

  // prologue: t0 full (8) + t1 sans A-h1 (6) = 14 loads; wait all but t1's 6
  SCA(A0OFF, 0, 0); SCA(A0OFF, 1, 0);
  SCB(B0OFF, 0, 0); SCB(B0OFF, 1, 0);
  SCB(B0OFF, 2, 0); SCB(B0OFF, 3, 0);
  SCA(A0OFF, 2, 0); SCA(A0OFF, 3, 0);
  SCA(A1OFF, 0, 64); SCA(A1OFF, 1, 64);
  SCB(B1OFF, 0, 64); SCB(B1OFF, 1, 64);
  SCB(B1OFF, 2, 64); SCB(B1OFF, 3, 64);
  GVMC(6);
  GBAR();
  LDX(A0OFF, 0);  // X0(t0)
  LDB(B0OFF, 0);  // B0(t0)

  constexpr int G = KDIM / 128;  // groups of 2 K-tiles
#pragma unroll 1
  for (int g = 0; g < G - 1; ++g) {
    const int kA = g * 128 + 64;   // t1 = 2g+1 (buf1): A-h1 staged ph1
    const int kB = g * 128 + 128;  // t2 = 2g+2 (buf0): staged ph2-5
    const int kC = g * 128 + 192;  // t3 = 2g+3 (buf1): 3 halves, ph6-8
    // ph1: MM(0,0)=X0*B0; read B1 (for ph2)
    SCA(A1OFF, 2, kA); SCA(A1OFF, 3, kA);
    LDB(B0OFF, 1);
    MM4(0, 0);
    GBAR();
    // ph2: MM(0,1)=X0*B1; post-MM read X1 (SSA: MM reads old Xf)
    SCA(A0OFF, 0, kB); SCA(A0OFF, 1, kB);
    MM4(0, 1);
    LDX(A0OFF, 1);
    GBAR();
    // ph3: MM(1,0)=X1*B0
    SCB(B0OFF, 0, kB); SCB(B0OFF, 1, kB);
    MM4(1, 0);
    GBAR();
    // ph4: MM(1,1)=X1*B1 first; then vmc6+BAR (t1 resident all-waves);
    // then read X0',B0' (drain under ph5's MM issue).
    SCB(B0OFF, 2, kB); SCB(B0OFF, 3, kB);
    MM4(1, 1);
    GVMC(6);
    GBAR();
    LDX(A1OFF, 0);
    LDB(B1OFF, 0);
    GBAR();
    // ph5: MM(0,0)'=X0'*B0'; read B1'
    SCA(A0OFF, 2, kB); SCA(A0OFF, 3, kB);
    LDB(B1OFF, 1);
    MM4(0, 0);
    GBAR();
    // ph6: MM(0,1)'=X0'*B1'; post-MM read X1'
    SCA(A1OFF, 0, kC); SCA(A1OFF, 1, kC);
    MM4(0, 1);
    LDX(A1OFF, 1);
    GBAR();
    // ph7: MM(1,0)'=X1'*B0'
    SCB(B1OFF, 0, kC); SCB(B1OFF, 1, kC);
    MM4(1, 0);
    GBAR();
    // ph8: MM(1,1)'=X1'*B1' first; vmc6+BAR (t2 resident); read X0'',B0''
    SCB(B1OFF, 2, kC); SCB(B1OFF, 3, kC);
    MM4(1, 1);
    GVMC(6);
    GBAR();
    LDX(A0OFF, 0);
    LDB(B0OFF, 0);
    GBAR();
  }
  // tail group: t_{2G-2}(buf0), t_{2G-1}(buf1); only t_{2G-1} A-h1 to stage
  {
    const int kA = KDIM - 64;
    SCA(A1OFF, 2, kA); SCA(A1OFF, 3, kA);
    LDB(B0OFF, 1);
    MM4(0, 0);
    GBAR();
    MM4(0, 1);
    LDX(A0OFF, 1);
    GBAR();
    MM4(1, 0);
    GBAR();
    MM4(1, 1);
    GVMC(0);
    GBAR();
    LDX(A1OFF, 0);
    LDB(B1OFF, 0);
    GBAR();
    LDB(B1OFF, 1);
    MM4(0, 0);
    GBAR();
    MM4(0, 1);
    LDX(A1OFF, 1);
    GBAR();
    MM4(1, 0);
    GBAR();
    MM4(1, 1);
  }
}

// ---- GEMM1: f16 chain, 256^2 8-phase core + quantize/flag/flush epilogue --
__global__ __launch_bounds__(512, 2) void gemm1_k(
    const unsigned short* __restrict__ xh, const unsigned short* __restrict__ ah,
    unsigned short* __restrict__ kb2, unsigned int* __restrict__ counts,
    unsigned int* __restrict__ lists) {
  __shared__ __align__(128) unsigned short smem[65536];  // 128 KB
  __shared__ unsigned int lmeta[2050];

  const int tid = threadIdx.x, lane = tid & 63, w = tid >> 6;
  const int wr = w >> 2, wc = w & 3;
  const int hi = lane >> 5, l31 = lane & 31;
  // XCD-bijective swizzle (m204; nwg=512, nwg%8==0, q=64)
  const int orig = blockIdx.y * 8 + blockIdx.x;
  const int swz = (orig & 7) * 64 + (orig >> 3);
  const int m0 = (swz >> 3) * 256, n0 = (swz & 7) * 256;
  const int bt = m0 >> 8;  // 256-row slab index 0..63

  f32x16 acc[4][2];
#pragma unroll
  for (int m = 0; m < 4; ++m)
#pragma unroll
    for (int n = 0; n < 2; ++n)
#pragma unroll
      for (int q = 0; q < 16; ++q) acc[m][n][q] = 0.0f;

  if (tid == 0) lmeta[0] = 0;  // published by core's prologue barrier

  gemm_core<D_DIM, true>(xh, m0, ah, n0, smem, acc, tid);

  // ---- epilogue: quantize -> bf16 2k in LDS (XOR-swz), flags, flush ------
  // 32x32 C/D: col = lane&31, row = (reg&3) + 8*(reg>>2) + 4*hi.
  __syncthreads();
  unsigned short* sq = smem;  // [256][256] bf16, chunk-swizzled
  unsigned int* mylist = lists + (size_t)bt * TILE_CAP;
#pragma unroll
  for (int a2 = 0; a2 < 4; ++a2)
#pragma unroll
    for (int nh = 0; nh < 2; ++nh) {
      const int rowb = (a2 >> 1) * 128 + wr * 64 + (a2 & 1) * 32 + 4 * hi;
      const int col = nh * 128 + wc * 32 + l31;
#pragma unroll
      for (int reg = 0; reg < 16; ++reg) {
        const int row = rowb + (reg & 3) + 8 * (reg >> 2);
        const float kr = acc[a2][nh][reg] * 20.0f;
        const float rr = rintf(kr);
        if (0.5f - fabsf(kr - rr) < 2e-3f) {  // r7-r24-validated window
          const unsigned int code =
              ((unsigned int)(m0 + row) << 11) | (unsigned int)(n0 + col);
          const unsigned int li = atomicAdd(&lmeta[0], 1u);  // LDS atomic
          if (li < LCAP) lmeta[1 + li] = code;
          else {
            const unsigned int gi = atomicAdd(&counts[bt], 1u);
            if (gi < TILE_CAP) mylist[gi] = code;
          }
        }
        // swizzled store: chunk (col>>3) with low 3 bits XOR (row&7)
        const int ch = col >> 3;
        const int csw = (ch & 24) | ((ch & 7) ^ (row & 7));
        sq[row * 256 + csw * 8 + (col & 7)] =
            bf16_rne((float)(2 * (int)rr));  // exact
      }
    }
  __syncthreads();
  if (tid == 0) {
    const unsigned int c = lmeta[0] < LCAP ? lmeta[0] : LCAP;
    lmeta[2049] = atomicAdd(&counts[bt], c);  // ONE global atomic per block
  }
  __syncthreads();
  {
    const unsigned int c = lmeta[0] < LCAP ? lmeta[0] : LCAP;
    const unsigned int base = lmeta[2049];
    for (unsigned int t = tid; t < c; t += 512)
      if (base + t < TILE_CAP) mylist[base + t] = lmeta[1 + t];
  }
  {
    const int row = tid >> 1, half = tid & 1;
    unsigned short* dst = kb2 + (size_t)(m0 + row) * A_ROWS + n0 + half * 128;
#pragma unroll
    for (int j = 0; j < 16; ++j) {
      const int creal = half * 16 + j;
      const int csw = (creal & 24) | ((creal & 7) ^ (row & 7));
      reinterpret_cast<int4*>(dst)[j] =
          *reinterpret_cast<const int4*>(sq + row * 256 + csw * 8);
    }
  }
}

// ---- fixup: wave-per-flag, 2-deep pipelined gather, bucketed by slab ------
__global__ __launch_bounds__(256) void fixup_k(
    const float* __restrict__ x, const float* __restrict__ anc,
    const double* __restrict__ inv_norms, const unsigned int* __restrict__ counts,
    const unsigned int* __restrict__ lists, unsigned short* __restrict__ kb2) {
  const int bt = blockIdx.x & 63;
  const int sub = blockIdx.x >> 6;          // 0..63
  unsigned int cnt = counts[bt];
  if (cnt > TILE_CAP) cnt = TILE_CAP;
  const unsigned int* mylist = lists + (size_t)bt * TILE_CAP;
  const int lane = threadIdx.x & 63;
  const int wib = threadIdx.x >> 6;         // wave in block 0..3
  unsigned int i = (unsigned int)(sub * 4 + wib);
  if (i >= cnt) return;
  const unsigned int stride = 256;          // 64 subs x 4 waves

  unsigned int code = mylist[i];
  float4 xc0, xc1, xc2, xc3, ac0, ac1, ac2, ac3;
  {
    const int b = code >> 11, a = code & 2047;
    const float4* xp = reinterpret_cast<const float4*>(x + (size_t)b * D_DIM) + lane;
    const float4* ap = reinterpret_cast<const float4*>(anc + (size_t)a * D_DIM) + lane;
    xc0 = xp[0]; xc1 = xp[64]; xc2 = xp[128]; xc3 = xp[192];
    ac0 = ap[0]; ac1 = ap[64]; ac2 = ap[128]; ac3 = ap[192];
  }
  for (;;) {
    const unsigned int inext = i + stride;
    const bool have = inext < cnt;
    unsigned int coden = 0;
    float4 xn0, xn1, xn2, xn3, an0, an1, an2, an3;
    if (have) {  // issue next flag's gather (hides under current compute)
      coden = mylist[inext];
      const int b = coden >> 11, a = coden & 2047;
      const float4* xp = reinterpret_cast<const float4*>(x + (size_t)b * D_DIM) + lane;
      const float4* ap = reinterpret_cast<const float4*>(anc + (size_t)a * D_DIM) + lane;
      xn0 = xp[0]; xn1 = xp[64]; xn2 = xp[128]; xn3 = xp[192];
      an0 = ap[0]; an1 = ap[64]; an2 = ap[128]; an3 = ap[192];
    }
    {
      double p0 = (double)xc0.x * (double)ac0.x + (double)xc0.y * (double)ac0.y +
                  (double)xc0.z * (double)ac0.z + (double)xc0.w * (double)ac0.w;
      double p1 = (double)xc1.x * (double)ac1.x + (double)xc1.y * (double)ac1.y +
                  (double)xc1.z * (double)ac1.z + (double)xc1.w * (double)ac1.w;
      double p2 = (double)xc2.x * (double)ac2.x + (double)xc2.y * (double)ac2.y +
                  (double)xc2.z * (double)ac2.z + (double)xc2.w * (double)ac2.w;
      double p3 = (double)xc3.x * (double)ac3.x + (double)xc3.y * (double)ac3.y +
                  (double)xc3.z * (double)ac3.z + (double)xc3.w * (double)ac3.w;
      double s = (p0 + p1) + (p2 + p3);
      s += __shfl_xor(s, 32);
      s += __shfl_xor(s, 16);
      s += __shfl_xor(s, 8);
      s += __shfl_xor(s, 4);
      s += __shfl_xor(s, 2);
      s += __shfl_xor(s, 1);
      if (lane == 0) {
        const int b = code >> 11, a = code & 2047;
        const double sim = s * inv_norms[b] * inv_norms[B_ROWS + a];
        const double kr = sim / 0.05;
        const double r = rint(kr);
        const double fr = kr - r;
        int k2 = 2 * (int)r;
        if (0.5 - fabs(fr) < 2.5e-6) k2 += (fr > 0.0) ? 1 : -1;  // midpoint hedge
        kb2[(size_t)b * A_ROWS + a] = bf16_rne((float)k2);       // exact int
      }
    }
    if (!have) break;
    i = inext; code = coden;
    xc0 = xn0; xc1 = xn1; xc2 = xn2; xc3 = xn3;
    ac0 = an0; ac1 = an1; ac2 = an2; ac3 = an3;
  }
}

// ---- GEMM2: bf16 chain, K=2048, 32x32 core, out = .025*k2@vbT -------------
__global__ __launch_bounds__(512, 2) void gemm2_k(
    const unsigned short* __restrict__ kb2, const unsigned short* __restrict__ vbT,
    float* __restrict__ out) {
  __shared__ __align__(128) unsigned short smem[65536];  // 128 KB

  const int tid = threadIdx.x, lane = tid & 63, w = tid >> 6;
  const int wr = w >> 2, wc = w & 3;
  const int hi = lane >> 5, l31 = lane & 31;
  // XCD-bijective swizzle (nwg=256, q=32)
  const int orig = blockIdx.y * 4 + blockIdx.x;
  const int swz = (orig & 7) * 32 + (orig >> 3);
  const int m0 = (swz >> 2) * 256, h0 = (swz & 3) * 256;

  f32x16 acc[4][2];
#pragma unroll
  for (int m = 0; m < 4; ++m)
#pragma unroll
    for (int n = 0; n < 2; ++n)
#pragma unroll
      for (int q = 0; q < 16; ++q) acc[m][n][q] = 0.0f;

  gemm_core<A_ROWS, false>(kb2, m0, vbT, h0, smem, acc, tid);

#pragma unroll
  for (int a2 = 0; a2 < 4; ++a2)
#pragma unroll
    for (int nh = 0; nh < 2; ++nh) {
      const int rowb = (a2 >> 1) * 128 + wr * 64 + (a2 & 1) * 32 + 4 * hi;
      const int col = h0 + nh * 128 + wc * 32 + l31;
#pragma unroll
      for (int reg = 0; reg < 16; ++reg) {
        const int row = rowb + (reg & 3) + 8 * (reg >> 2);
        out[(size_t)(m0 + row) * H_DIM + col] = 0.025f * acc[a2][nh][reg];
      }
    }
}

// ---------------------------------------------------------------------------
extern "C" void kernel_launch(void* const* d_in, const int* in_sizes, int n_in,
                              void* d_out, int out_size, void* d_ws, size_t ws_size,
                              hipStream_t stream) {
  const float* x      = (const float*)d_in[0];
  const float* anc    = (const float*)d_in[1];
  const float* values = (const float*)d_in[2];
  float* out = (float*)d_out;

  char* ws = (char*)d_ws;
  double* inv_norms    = (double*)(ws);
  unsigned int* counts = (unsigned int*)(ws + 0x24000);
  unsigned int* lists  = (unsigned int*)(ws + 0x24200);
  unsigned short* xh   = (unsigned short*)(ws + 0x324000);
  unsigned short* ah   = (unsigned short*)(ws + 0x2324000);
  unsigned short* vbT  = (unsigned short*)(ws + 0x2724000);
  unsigned short* kb2  = (unsigned short*)(ws + 0x2B24000);

  normprep_k<<<B_ROWS, 256, 0, stream>>>(x, inv_norms, xh);
  normprep_k<<<A_ROWS, 256, 0, stream>>>(anc, inv_norms + B_ROWS, ah);
  prep_vt_k<<<dim3(H_DIM / 16, A_ROWS / 16), dim3(16, 16), 0, stream>>>(values, vbT, counts);
  gemm1_k<<<dim3(A_ROWS / 256, B_ROWS / 256), 512, 0, stream>>>(xh, ah, kb2, counts, lists);
  fixup_k<<<4096, 256, 0, stream>>>(x, anc, inv_norms, counts, lists, kb2);
  gemm2_k<<<dim3(H_DIM / 256, B_ROWS / 256), 512, 0, stream>>>(kb2, vbT, out);
}

// Round 9
// 289.807 us; speedup vs baseline: 1.0552x; 1.0552x over previous
//
#include <hip/hip_runtime.h>
#include <math.h>

// RelativeAttention: out = round((x_n @ a_n^T)/0.05)*0.05 @ values
//
// Round 26 (from r25 REGRESS 305.8 -- 32x32 frag reads = 25x bank conflicts,
// reverted): r24 core (16x16, conflict-free, 285.0us best) restructured into
// the m201 DOUBLE-BARRIER phase form -- the one untried axis:
//   per phase: {ds_read THIS phase's frags; stage; [lgkmcnt(8) if 12 reads];
//               BAR1; lgkmcnt(0)+sched_barrier; setprio(1); 16 MFMA;
//               setprio(0); [vmcnt(6) at ph4/ph8]; BAR2}
// Pure-MFMA region between barriers (m196/m218 measured this interleave as
// the +28-73% lever). Stage plan / vmcnt accounting / register budget are
// r24's (re-verified: ph4/ph8 vmcnt(6)+BAR2 precede next-buffer reads; slot
// WAR guarded by BAR2 after per-wave lgkm0 drain; SSA preserves dataflow;
// MFMA K-order per accumulator unchanged -> bit-identical kb2, absmax canary
// 2.685547e-3). Epilogues, fixup (r24 pipelined), preps: r24 exact.
//
// ws layout (bytes):
//   [0x0,       0x24000)   inv_norms f64 (16384 x | 2048 anchors)
//   [0x24000,   0x24200)   counts u32[64] (128 slots reserved)
//   [0x24200,   0x224200)  lists u32[64][8192]
//   [0x324000,  0x2324000) xh f16 [16384][1024] (32MB)
//   [0x2324000, 0x2724000) ah f16 [2048][1024] (4MB)
//   [0x2724000, 0x2B24000) vbT bf16 [1024][2048] (values^T, 4MB)
//   [0x2B24000, 0x6B24000) kb2 bf16 [16384][2048] (2*bin, odd = midpoint)

#define B_ROWS 16384
#define A_ROWS 2048
#define D_DIM  1024
#define H_DIM  1024
#define TILE_CAP 8192u
#define LCAP 2040u

typedef __attribute__((ext_vector_type(8))) short short8;
typedef __attribute__((ext_vector_type(8))) _Float16 half8;
typedef __attribute__((ext_vector_type(4))) float f32x4;

__device__ inline unsigned short bf16_rne(float f) {
  unsigned int u = __float_as_uint(f);
  unsigned int r = (u + 0x7FFFu + ((u >> 16) & 1u)) >> 16;
  return (unsigned short)r;
}
__device__ inline unsigned short f16_bits(float f) {
  _Float16 h = (_Float16)f;
  return __builtin_bit_cast(unsigned short, h);
}
__device__ inline void gload16(const void* g, void* l) {
  __builtin_amdgcn_global_load_lds(
      (const __attribute__((address_space(1))) unsigned int*)g,
      (__attribute__((address_space(3))) unsigned int*)l, 16, 0, 0);
}

template <bool F16>
__device__ __forceinline__ f32x4 mm16(short8 a, short8 b, f32x4 c) {
  if constexpr (F16)
    return __builtin_amdgcn_mfma_f32_16x16x32_f16(
        __builtin_bit_cast(half8, a), __builtin_bit_cast(half8, b), c, 0, 0, 0);
  else
    return __builtin_amdgcn_mfma_f32_16x16x32_bf16(a, b, c, 0, 0, 0);
}

// ------------- fused: norm (f64, r3-proven tree) + f16 convert -------------
__global__ __launch_bounds__(256) void normprep_k(
    const float* __restrict__ src, double* __restrict__ inv_out,
    unsigned short* __restrict__ dst) {
#pragma clang fp contract(off)
  const int r = blockIdx.x;
  const int t = threadIdx.x;
  const float4 v = reinterpret_cast<const float4*>(src + (size_t)r * D_DIM)[t];
  double s = (double)v.x * (double)v.x + (double)v.y * (double)v.y +
             (double)v.z * (double)v.z + (double)v.w * (double)v.w;
#pragma unroll
  for (int off = 32; off > 0; off >>= 1) s += __shfl_down(s, off);
  __shared__ double red[4];
  __shared__ double sinv;
  if ((t & 63) == 0) red[t >> 6] = s;
  __syncthreads();
  if (t == 0) {
    const double n = sqrt(red[0] + red[1] + red[2] + red[3]);
    const double inv = 1.0 / fmax(n, 1e-12);
    inv_out[r] = inv;
    sinv = inv;
  }
  __syncthreads();
  const float invn = (float)sinv;
  ushort4 o;
  o.x = f16_bits(v.x * invn); o.y = f16_bits(v.y * invn);
  o.z = f16_bits(v.z * invn); o.w = f16_bits(v.w * invn);
  reinterpret_cast<ushort4*>(dst + (size_t)r * D_DIM)[t] = o;
}

// ---------------------- prep: values^T as bf16 (+ zero counts) -------------
__global__ void prep_vt_k(const float* __restrict__ values,
                          unsigned short* __restrict__ vbT,
                          unsigned int* __restrict__ counts) {
  __shared__ float s[16][17];
  const int tx = threadIdx.x, ty = threadIdx.y;
  if (blockIdx.x == 0 && blockIdx.y == 0) {
    const int ft = ty * 16 + tx;
    if (ft < 128) counts[ft] = 0;
  }
  const int h0 = blockIdx.x * 16, a0 = blockIdx.y * 16;
  s[ty][tx] = values[(size_t)(a0 + ty) * H_DIM + h0 + tx];
  __syncthreads();
  vbT[(size_t)(h0 + ty) * A_ROWS + a0 + tx] = bf16_rne(s[tx][ty]);
}

// ------ 256x256 / BK=64 / 8-wave / 8-phase double-barrier GEMM core -------
// LDS: buf0 {A:[256][64] @0, B @16384}, buf1 {A @32768, B @49152} (shorts).
// Chunk-XOR swizzle: row r's chunk k (16B) lives at slot k^(r&7); staging
// pre-swizzles the per-lane GLOBAL source so the LDS dest stays linear.
#define GBAR() do { __builtin_amdgcn_s_barrier(); \
                    asm volatile("" ::: "memory"); } while (0)
#define GVMC(n) asm volatile("s_waitcnt vmcnt(" #n ")" ::: "memory")
#define LGK8() asm volatile("s_waitcnt lgkmcnt(8)" ::: "memory")
#define LG0SB() do { asm volatile("s_waitcnt lgkmcnt(0)" ::: "memory"); \
                     __builtin_amdgcn_sched_barrier(0); } while (0)

#define SCA(buf, c, kv) gload16(aS + (size_t)(c) * 64 * KDIM + (kv), \
                                (buf) + (c) * 4096 + tid * 8)
#define SCB(buf, c, kv) gload16(bS + (size_t)(c) * 64 * KDIM + (kv), \
                                (buf) + (c) * 4096 + tid * 8)

// frag reads: plain C++ short8 loads off precomputed swizzled bases.
#define LDX(pk0, pk1, mh) do { \
    _Pragma("unroll") for (int m_ = 0; m_ < 4; ++m_) { \
      Xf[0][m_] = *reinterpret_cast<const short8*>((pk0) + (mh) * 8192 + m_ * 1024); \
      Xf[1][m_] = *reinterpret_cast<const short8*>((pk1) + (mh) * 8192 + m_ * 1024); \
    } } while (0)

#define LDB(pk0, pk1, nh) do { \
    _Pragma("unroll") for (int n_ = 0; n_ < 2; ++n_) { \
      Bf[nh][0][n_] = *reinterpret_cast<const short8*>((pk0) + (nh) * 8192 + n_ * 1024); \
      Bf[nh][1][n_] = *reinterpret_cast<const short8*>((pk1) + (nh) * 8192 + n_ * 1024); \
    } } while (0)

#define MM4(mh, nh) do { \
    __builtin_amdgcn_s_setprio(1); \
    _Pragma("unroll") for (int ki_ = 0; ki_ < 2; ++ki_) \
    _Pragma("unroll") for (int m_ = 0; m_ < 4; ++m_) \
    _Pragma("unroll") for (int n_ = 0; n_ < 2; ++n_) \
      acc[(mh) * 4 + m_][(nh) * 2 + n_] = mm16<F16>( \
          Xf[ki_][m_], Bf[nh][ki_][n_], acc[(mh) * 4 + m_][(nh) * 2 + n_]); \
    __builtin_amdgcn_s_setprio(0); \
  } while (0)

template <int KDIM, bool F16>
__device__ __forceinline__ void gemm_core(
    const unsigned short* __restrict__ Amat, int m0,
    const unsigned short* __restrict__ Bmat, int n0,
    unsigned short* smem, f32x4 (&acc)[8][4], const int tid) {
  static_assert(KDIM % 128 == 0 && KDIM >= 256, "KDIM");
  const int lane = tid & 63, w = tid >> 6;
  const int wr = w >> 2, wc = w & 3;
  const int cl = lane & 15, kg = lane >> 4;
  unsigned short* const A0b = smem;
  unsigned short* const B0b = smem + 16384;
  unsigned short* const A1b = smem + 32768;
  unsigned short* const B1b = smem + 49152;
  // staging geometry: call c covers rows c*64 + (tid>>3), chunk slot tid&7;
  // source chunk = slot ^ (row&7); (c*64)&7==0 so the XOR is c-invariant.
  const int srow = tid >> 3;
  const int tcs = (tid & 7) ^ (srow & 7);
  const unsigned short* aS = Amat + (size_t)(m0 + srow) * KDIM + tcs * 8;
  const unsigned short* bS = Bmat + (size_t)(n0 + srow) * KDIM + tcs * 8;

  // frag-read swizzle constants: row&7 == cl&7 for all frag rows, so the
  // chunk index is lane-constant: cc = (ki*4+kg)^(cl&7); ki flips ^32 shorts.
  const int cc0 = kg ^ (cl & 7);
  const int oA0 = (wr * 64 + cl) * 64 + cc0 * 8;
  const int oA1 = oA0 ^ 32;
  const int oB0 = (wc * 32 + cl) * 64 + cc0 * 8;
  const int oB1 = oB0 ^ 32;
  const unsigned short* const pA0k0 = A0b + oA0;
  const unsigned short* const pA0k1 = A0b + oA1;
  const unsigned short* const pA1k0 = A1b + oA0;
  const unsigned short* const pA1k1 = A1b + oA1;
  const unsigned short* const pB0k0 = B0b + oB0;
  const unsigned short* const pB0k1 = B0b + oB1;
  const unsigned short* const pB1k0 = B1b + oB0;
  const unsigned short* const pB1k1 = B1b + oB1;

  short8 Xf[2][4], Bf[2][2][2];

  // prologue: t0 full (8) + t1 sans A-h1 (6) = 14 loads; wait all but t1's 6
  SCA(A0b, 0, 0); SCA(A0b, 1, 0);
  SCB(B0b, 0, 0); SCB(B0b, 1, 0);
  SCB(B0b, 2, 0); SCB(B0b, 3, 0);
  SCA(A0b, 2, 0); SCA(A0b, 3, 0);
  SCA(A1b, 0, 64); SCA(A1b, 1, 64);
  SCB(B1b, 0, 64); SCB(B1b, 1, 64);
  SCB(B1b, 2, 64); SCB(B1b, 3, 64);
  GVMC(6);
  GBAR();

  constexpr int G = KDIM / 128;  // groups of 2 K-tiles
#pragma unroll 1
  for (int g = 0; g < G - 1; ++g) {
    const int kA = g * 128 + 64;   // t1 = 2g+1 (buf1): A-h1 staged ph1
    const int kB = g * 128 + 128;  // t2 = 2g+2 (buf0): staged ph2-5
    const int kC = g * 128 + 192;  // t3 = 2g+3 (buf1): 3 halves, ph6-8
    // ph1: read X0,B0(t0); stage A1-h1; pure-MFMA region MM(0,0)
    LDX(pA0k0, pA0k1, 0);
    LDB(pB0k0, pB0k1, 0);
    SCA(A1b, 2, kA); SCA(A1b, 3, kA);
    LGK8(); GBAR(); LG0SB(); MM4(0, 0); GBAR();
    // ph2: read B1(t0); stage A0-h0(t2); MM(0,1)
    LDB(pB0k0, pB0k1, 1);
    SCA(A0b, 0, kB); SCA(A0b, 1, kB);
    GBAR(); LG0SB(); MM4(0, 1); GBAR();
    // ph3: read X1(t0); stage B0-h0(t2); MM(1,0)
    LDX(pA0k0, pA0k1, 1);
    SCB(B0b, 0, kB); SCB(B0b, 1, kB);
    GBAR(); LG0SB(); MM4(1, 0); GBAR();
    // ph4: no reads; stage B0-h1(t2); MM(1,1); vmcnt(6) -> t1 resident
    SCB(B0b, 2, kB); SCB(B0b, 3, kB);
    GBAR(); MM4(1, 1); GVMC(6); GBAR();
    // ph5: read X0',B0'(t1); stage A0-h1(t2); MM(0,0)'
    LDX(pA1k0, pA1k1, 0);
    LDB(pB1k0, pB1k1, 0);
    SCA(A0b, 2, kB); SCA(A0b, 3, kB);
    LGK8(); GBAR(); LG0SB(); MM4(0, 0); GBAR();
    // ph6: read B1'(t1); stage A1-h0(t3); MM(0,1)'
    LDB(pB1k0, pB1k1, 1);
    SCA(A1b, 0, kC); SCA(A1b, 1, kC);
    GBAR(); LG0SB(); MM4(0, 1); GBAR();
    // ph7: read X1'(t1); stage B1-h0(t3); MM(1,0)'
    LDX(pA1k0, pA1k1, 1);
    SCB(B1b, 0, kC); SCB(B1b, 1, kC);
    GBAR(); LG0SB(); MM4(1, 0); GBAR();
    // ph8: stage B1-h1(t3); MM(1,1)'; vmcnt(6) -> t2 resident
    SCB(B1b, 2, kC); SCB(B1b, 3, kC);
    GBAR(); MM4(1, 1); GVMC(6); GBAR();
  }
  // tail group: t_{2G-2}(buf0), t_{2G-1}(buf1); only t_{2G-1} A-h1 to stage
  {
    const int kA = KDIM - 64;
    LDX(pA0k0, pA0k1, 0);
    LDB(pB0k0, pB0k1, 0);
    SCA(A1b, 2, kA); SCA(A1b, 3, kA);
    LGK8(); GBAR(); LG0SB(); MM4(0, 0); GBAR();
    LDB(pB0k0, pB0k1, 1);
    GBAR(); LG0SB(); MM4(0, 1); GBAR();
    LDX(pA0k0, pA0k1, 1);
    GBAR(); LG0SB(); MM4(1, 0); GBAR();
    GBAR(); MM4(1, 1); GVMC(0); GBAR();
    LDX(pA1k0, pA1k1, 0);
    LDB(pB1k0, pB1k1, 0);
    LGK8(); GBAR(); LG0SB(); MM4(0, 0); GBAR();
    LDB(pB1k0, pB1k1, 1);
    GBAR(); LG0SB(); MM4(0, 1); GBAR();
    LDX(pA1k0, pA1k1, 1);
    GBAR(); LG0SB(); MM4(1, 0); GBAR();
    MM4(1, 1);
  }
}

// ---- GEMM1: f16 chain, 256^2 8-phase core + quantize/flag/flush epilogue --
__global__ __launch_bounds__(512, 2) void gemm1_k(
    const unsigned short* __restrict__ xh, const unsigned short* __restrict__ ah,
    unsigned short* __restrict__ kb2, unsigned int* __restrict__ counts,
    unsigned int* __restrict__ lists) {
  __shared__ __align__(128) unsigned short smem[65536];  // 128 KB
  __shared__ unsigned int lmeta[2050];

  const int tid = threadIdx.x, lane = tid & 63, w = tid >> 6;
  const int wr = w >> 2, wc = w & 3;
  const int cl = lane & 15, kg = lane >> 4;
  // XCD-bijective swizzle (m204; nwg=512, nwg%8==0, q=64)
  const int orig = blockIdx.y * 8 + blockIdx.x;
  const int swz = (orig & 7) * 64 + (orig >> 3);
  const int m0 = (swz >> 3) * 256, n0 = (swz & 7) * 256;
  const int bt = m0 >> 8;  // 256-row slab index 0..63

  f32x4 acc[8][4];
#pragma unroll
  for (int m = 0; m < 8; ++m)
#pragma unroll
    for (int n = 0; n < 4; ++n)
#pragma unroll
      for (int q = 0; q < 4; ++q) acc[m][n][q] = 0.0f;

  if (tid == 0) lmeta[0] = 0;  // published by core's prologue barrier

  gemm_core<D_DIM, true>(xh, m0, ah, n0, smem, acc, tid);

  // ---- epilogue: quantize -> bf16 2k in LDS (XOR-swz), flags, flush ------
  __syncthreads();
  unsigned short* sq = smem;  // [256][256] bf16, chunk-swizzled
  unsigned int* mylist = lists + (size_t)bt * TILE_CAP;
#pragma unroll
  for (int mi = 0; mi < 8; ++mi)
#pragma unroll
    for (int ni = 0; ni < 4; ++ni) {
      const int rowb = (mi >> 2) * 128 + wr * 64 + (mi & 3) * 16 + kg * 4;
      const int col = (ni >> 1) * 128 + wc * 32 + (ni & 1) * 16 + cl;
#pragma unroll
      for (int reg = 0; reg < 4; ++reg) {
        const int row = rowb + reg;
        const float kr = acc[mi][ni][reg] * 20.0f;
        const float rr = rintf(kr);
        if (0.5f - fabsf(kr - rr) < 2e-3f) {  // r7-r24-validated window
          const unsigned int code =
              ((unsigned int)(m0 + row) << 11) | (unsigned int)(n0 + col);
          const unsigned int li = atomicAdd(&lmeta[0], 1u);  // LDS atomic
          if (li < LCAP) lmeta[1 + li] = code;
          else {
            const unsigned int gi = atomicAdd(&counts[bt], 1u);
            if (gi < TILE_CAP) mylist[gi] = code;
          }
        }
        // swizzled store: chunk (col>>3) with low 3 bits XOR (row&7)
        const int ch = col >> 3;
        const int csw = (ch & 24) | ((ch & 7) ^ (row & 7));
        sq[row * 256 + csw * 8 + (col & 7)] =
            bf16_rne((float)(2 * (int)rr));  // exact
      }
    }
  __syncthreads();
  if (tid == 0) {
    const unsigned int c = lmeta[0] < LCAP ? lmeta[0] : LCAP;
    lmeta[2049] = atomicAdd(&counts[bt], c);  // ONE global atomic per block
  }
  __syncthreads();
  {
    const unsigned int c = lmeta[0] < LCAP ? lmeta[0] : LCAP;
    const unsigned int base = lmeta[2049];
    for (unsigned int t = tid; t < c; t += 512)
      if (base + t < TILE_CAP) mylist[base + t] = lmeta[1 + t];
  }
  {
    const int row = tid >> 1, half = tid & 1;
    unsigned short* dst = kb2 + (size_t)(m0 + row) * A_ROWS + n0 + half * 128;
#pragma unroll
    for (int j = 0; j < 16; ++j) {
      const int creal = half * 16 + j;
      const int csw = (creal & 24) | ((creal & 7) ^ (row & 7));
      reinterpret_cast<int4*>(dst)[j] =
          *reinterpret_cast<const int4*>(sq + row * 256 + csw * 8);
    }
  }
}

// ---- fixup: wave-per-flag, 2-deep pipelined gather, bucketed by slab ------
__global__ __launch_bounds__(256) void fixup_k(
    const float* __restrict__ x, const float* __restrict__ anc,
    const double* __restrict__ inv_norms, const unsigned int* __restrict__ counts,
    const unsigned int* __restrict__ lists, unsigned short* __restrict__ kb2) {
  const int bt = blockIdx.x & 63;
  const int sub = blockIdx.x >> 6;          // 0..63
  unsigned int cnt = counts[bt];
  if (cnt > TILE_CAP) cnt = TILE_CAP;
  const unsigned int* mylist = lists + (size_t)bt * TILE_CAP;
  const int lane = threadIdx.x & 63;
  const int wib = threadIdx.x >> 6;         // wave in block 0..3
  unsigned int i = (unsigned int)(sub * 4 + wib);
  if (i >= cnt) return;
  const unsigned int stride = 256;          // 64 subs x 4 waves

  unsigned int code = mylist[i];
  float4 xc0, xc1, xc2, xc3, ac0, ac1, ac2, ac3;
  {
    const int b = code >> 11, a = code & 2047;
    const float4* xp = reinterpret_cast<const float4*>(x + (size_t)b * D_DIM) + lane;
    const float4* ap = reinterpret_cast<const float4*>(anc + (size_t)a * D_DIM) + lane;
    xc0 = xp[0]; xc1 = xp[64]; xc2 = xp[128]; xc3 = xp[192];
    ac0 = ap[0]; ac1 = ap[64]; ac2 = ap[128]; ac3 = ap[192];
  }
  for (;;) {
    const unsigned int inext = i + stride;
    const bool have = inext < cnt;
    unsigned int coden = 0;
    float4 xn0, xn1, xn2, xn3, an0, an1, an2, an3;
    if (have) {  // issue next flag's gather (hides under current compute)
      coden = mylist[inext];
      const int b = coden >> 11, a = coden & 2047;
      const float4* xp = reinterpret_cast<const float4*>(x + (size_t)b * D_DIM) + lane;
      const float4* ap = reinterpret_cast<const float4*>(anc + (size_t)a * D_DIM) + lane;
      xn0 = xp[0]; xn1 = xp[64]; xn2 = xp[128]; xn3 = xp[192];
      an0 = ap[0]; an1 = ap[64]; an2 = ap[128]; an3 = ap[192];
    }
    {
      double p0 = (double)xc0.x * (double)ac0.x + (double)xc0.y * (double)ac0.y +
                  (double)xc0.z * (double)ac0.z + (double)xc0.w * (double)ac0.w;
      double p1 = (double)xc1.x * (double)ac1.x + (double)xc1.y * (double)ac1.y +
                  (double)xc1.z * (double)ac1.z + (double)xc1.w * (double)ac1.w;
      double p2 = (double)xc2.x * (double)ac2.x + (double)xc2.y * (double)ac2.y +
                  (double)xc2.z * (double)ac2.z + (double)xc2.w * (double)ac2.w;
      double p3 = (double)xc3.x * (double)ac3.x + (double)xc3.y * (double)ac3.y +
                  (double)xc3.z * (double)ac3.z + (double)xc3.w * (double)ac3.w;
      double s = (p0 + p1) + (p2 + p3);
      s += __shfl_xor(s, 32);
      s += __shfl_xor(s, 16);
      s += __shfl_xor(s, 8);
      s += __shfl_xor(s, 4);
      s += __shfl_xor(s, 2);
      s += __shfl_xor(s, 1);
      if (lane == 0) {
        const int b = code >> 11, a = code & 2047;
        const double sim = s * inv_norms[b] * inv_norms[B_ROWS + a];
        const double kr = sim / 0.05;
        const double r = rint(kr);
        const double fr = kr - r;
        int k2 = 2 * (int)r;
        if (0.5 - fabs(fr) < 2.5e-6) k2 += (fr > 0.0) ? 1 : -1;  // midpoint hedge
        kb2[(size_t)b * A_ROWS + a] = bf16_rne((float)k2);       // exact int
      }
    }
    if (!have) break;
    i = inext; code = coden;
    xc0 = xn0; xc1 = xn1; xc2 = xn2; xc3 = xn3;
    ac0 = an0; ac1 = an1; ac2 = an2; ac3 = an3;
  }
}

// ---- GEMM2: bf16 chain, K=2048, 256^2 8-phase core, out = .025*k2@vbT -----
__global__ __launch_bounds__(512, 2) void gemm2_k(
    const unsigned short* __restrict__ kb2, const unsigned short* __restrict__ vbT,
    float* __restrict__ out) {
  __shared__ __align__(128) unsigned short smem[65536];  // 128 KB

  const int tid = threadIdx.x, lane = tid & 63, w = tid >> 6;
  const int wr = w >> 2, wc = w & 3;
  const int cl = lane & 15, kg = lane >> 4;
  // XCD-bijective swizzle (nwg=256, q=32)
  const int orig = blockIdx.y * 4 + blockIdx.x;
  const int swz = (orig & 7) * 32 + (orig >> 3);
  const int m0 = (swz >> 2) * 256, h0 = (swz & 3) * 256;

  f32x4 acc[8][4];
#pragma unroll
  for (int m = 0; m < 8; ++m)
#pragma unroll
    for (int n = 0; n < 4; ++n)
#pragma unroll
      for (int q = 0; q < 4; ++q) acc[m][n][q] = 0.0f;

  gemm_core<A_ROWS, false>(kb2, m0, vbT, h0, smem, acc, tid);

#pragma unroll
  for (int mi = 0; mi < 8; ++mi)
#pragma unroll
    for (int ni = 0; ni < 4; ++ni) {
      const int rowb = (mi >> 2) * 128 + wr * 64 + (mi & 3) * 16 + kg * 4;
      const int col = (ni >> 1) * 128 + wc * 32 + (ni & 1) * 16 + cl;
#pragma unroll
      for (int reg = 0; reg < 4; ++reg)
        out[(size_t)(m0 + rowb + reg) * H_DIM + h0 + col] =
            0.025f * acc[mi][ni][reg];
    }
}

// ---------------------------------------------------------------------------
extern "C" void kernel_launch(void* const* d_in, const int* in_sizes, int n_in,
                              void* d_out, int out_size, void* d_ws, size_t ws_size,
                              hipStream_t stream) {
  const float* x      = (const float*)d_in[0];
  const float* anc    = (const float*)d_in[1];
  const float* values = (const float*)d_in[2];
  float* out = (float*)d_out;

  char* ws = (char*)d_ws;
  double* inv_norms    = (double*)(ws);
  unsigned int* counts = (unsigned int*)(ws + 0x24000);
  unsigned int* lists  = (unsigned int*)(ws + 0x24200);
  unsigned short* xh   = (unsigned short*)(ws + 0x324000);
  unsigned short* ah   = (unsigned short*)(ws + 0x2324000);
  unsigned short* vbT  = (unsigned short*)(ws + 0x2724000);
  unsigned short* kb2  = (unsigned short*)(ws + 0x2B24000);

  normprep_k<<<B_ROWS, 256, 0, stream>>>(x, inv_norms, xh);
  normprep_k<<<A_ROWS, 256, 0, stream>>>(anc, inv_norms + B_ROWS, ah);
  prep_vt_k<<<dim3(H_DIM / 16, A_ROWS / 16), dim3(16, 16), 0, stream>>>(values, vbT, counts);
  gemm1_k<<<dim3(A_ROWS / 256, B_ROWS / 256), 512, 0, stream>>>(xh, ah, kb2, counts, lists);
  fixup_k<<<4096, 256, 0, stream>>>(x, anc, inv_norms, counts, lists, kb2);
  gemm2_k<<<dim3(H_DIM / 256, B_ROWS / 256), 512, 0, stream>>>(kb2, vbT, out);
}

// Round 10
// 278.614 us; speedup vs baseline: 1.0976x; 1.0402x over previous
//
#include <hip/hip_runtime.h>
#include <math.h>

// RelativeAttention: out = round((x_n @ a_n^T)/0.05)*0.05 @ values
//
// Round 27 (from r26 null @ 289.8; r24 best @ 285.0): revert core to r24
// (single-barrier read-ahead 8-phase, 16x16, conflict-free) -- SIX schedule
// variants all 110-120us, family closed. Periphery only:
//  - prep_k: normprep_x + normprep_a + prep_vt merged into ONE launch
//    (16384 + 2048 + 8192 blocks, branch on blockIdx): saves 2 launch gaps
//    and overlaps the small preps inside normprep_x's BW-bound tail.
//  - fixup: 8192 blocks (stride 512, was 256): 2x TLP for the latency-bound
//    gather, ~4 flags/wave so the r24-proven 2-deep pipeline still applies.
//  - gemm1/gemm2/epilogues byte-identical to r24 (absmax canary 2.685547e-3).
//
// ws layout (bytes):
//   [0x0,       0x24000)   inv_norms f64 (16384 x | 2048 anchors)
//   [0x24000,   0x24200)   counts u32[64] (128 slots reserved)
//   [0x24200,   0x224200)  lists u32[64][8192]
//   [0x324000,  0x2324000) xh f16 [16384][1024] (32MB)
//   [0x2324000, 0x2724000) ah f16 [2048][1024] (4MB)
//   [0x2724000, 0x2B24000) vbT bf16 [1024][2048] (values^T, 4MB)
//   [0x2B24000, 0x6B24000) kb2 bf16 [16384][2048] (2*bin, odd = midpoint)

#define B_ROWS 16384
#define A_ROWS 2048
#define D_DIM  1024
#define H_DIM  1024
#define TILE_CAP 8192u
#define LCAP 2040u

typedef __attribute__((ext_vector_type(8))) short short8;
typedef __attribute__((ext_vector_type(8))) _Float16 half8;
typedef __attribute__((ext_vector_type(4))) float f32x4;

__device__ inline unsigned short bf16_rne(float f) {
  unsigned int u = __float_as_uint(f);
  unsigned int r = (u + 0x7FFFu + ((u >> 16) & 1u)) >> 16;
  return (unsigned short)r;
}
__device__ inline unsigned short f16_bits(float f) {
  _Float16 h = (_Float16)f;
  return __builtin_bit_cast(unsigned short, h);
}
__device__ inline void gload16(const void* g, void* l) {
  __builtin_amdgcn_global_load_lds(
      (const __attribute__((address_space(1))) unsigned int*)g,
      (__attribute__((address_space(3))) unsigned int*)l, 16, 0, 0);
}

template <bool F16>
__device__ __forceinline__ f32x4 mm16(short8 a, short8 b, f32x4 c) {
  if constexpr (F16)
    return __builtin_amdgcn_mfma_f32_16x16x32_f16(
        __builtin_bit_cast(half8, a), __builtin_bit_cast(half8, b), c, 0, 0, 0);
  else
    return __builtin_amdgcn_mfma_f32_16x16x32_bf16(a, b, c, 0, 0, 0);
}

// ---- merged prep: norm+f16 (x rows | anchor rows) + values^T + zero cnts --
__global__ __launch_bounds__(256) void prep_k(
    const float* __restrict__ x, const float* __restrict__ anc,
    const float* __restrict__ values, double* __restrict__ inv_norms,
    unsigned short* __restrict__ xh, unsigned short* __restrict__ ah,
    unsigned short* __restrict__ vbT, unsigned int* __restrict__ counts) {
  const int blk = blockIdx.x;
  const int t = threadIdx.x;
  if (blk < B_ROWS + A_ROWS) {
    // ---- normprep branch (r3-proven f64 tree, fp-contract off) ----
#pragma clang fp contract(off)
    const bool isx = blk < B_ROWS;
    const int r = isx ? blk : blk - B_ROWS;
    const float* src = isx ? x + (size_t)r * D_DIM : anc + (size_t)r * D_DIM;
    double* inv_out = isx ? inv_norms + r : inv_norms + B_ROWS + r;
    unsigned short* dst = isx ? xh + (size_t)r * D_DIM : ah + (size_t)r * D_DIM;
    const float4 v = reinterpret_cast<const float4*>(src)[t];
    double s = (double)v.x * (double)v.x + (double)v.y * (double)v.y +
               (double)v.z * (double)v.z + (double)v.w * (double)v.w;
#pragma unroll
    for (int off = 32; off > 0; off >>= 1) s += __shfl_down(s, off);
    __shared__ double red[4];
    __shared__ double sinv;
    if ((t & 63) == 0) red[t >> 6] = s;
    __syncthreads();
    if (t == 0) {
      const double n = sqrt(red[0] + red[1] + red[2] + red[3]);
      const double inv = 1.0 / fmax(n, 1e-12);
      *inv_out = inv;
      sinv = inv;
    }
    __syncthreads();
    const float invn = (float)sinv;
    ushort4 o;
    o.x = f16_bits(v.x * invn); o.y = f16_bits(v.y * invn);
    o.z = f16_bits(v.z * invn); o.w = f16_bits(v.w * invn);
    reinterpret_cast<ushort4*>(dst)[t] = o;
  } else {
    // ---- prep_vt branch: 16x16 transpose tile (+ zero counts, tile 0) ----
    const int tile = blk - (B_ROWS + A_ROWS);
    const int tx = t & 15, ty = t >> 4;
    __shared__ float sm[16][17];
    if (tile == 0 && t < 128) counts[t] = 0;
    const int h0 = (tile & 63) * 16, a0 = (tile >> 6) * 16;
    sm[ty][tx] = values[(size_t)(a0 + ty) * H_DIM + h0 + tx];
    __syncthreads();
    vbT[(size_t)(h0 + ty) * A_ROWS + a0 + tx] = bf16_rne(sm[tx][ty]);
  }
}

// ------ 256x256 / BK=64 / 8-wave / 8-phase read-ahead GEMM core -----------
// LDS: buf0 {A:[256][64] @0, B @16384}, buf1 {A @32768, B @49152} (shorts).
// Chunk-XOR swizzle: row r's chunk k (16B) lives at slot k^(r&7); staging
// pre-swizzles the per-lane GLOBAL source so the LDS dest stays linear.
#define GBAR() do { __builtin_amdgcn_s_barrier(); \
                    asm volatile("" ::: "memory"); } while (0)
#define GVMC(n) asm volatile("s_waitcnt vmcnt(" #n ")" ::: "memory")

#define SCA(buf, c, kv) gload16(aS + (size_t)(c) * 64 * KDIM + (kv), \
                                (buf) + (c) * 4096 + tid * 8)
#define SCB(buf, c, kv) gload16(bS + (size_t)(c) * 64 * KDIM + (kv), \
                                (buf) + (c) * 4096 + tid * 8)

// frag reads: plain C++ short8 loads off precomputed swizzled bases;
// compiler inserts counted lgkmcnt and interleaves with MFMA.
#define LDX(pk0, pk1, mh) do { \
    _Pragma("unroll") for (int m_ = 0; m_ < 4; ++m_) { \
      Xf[0][m_] = *reinterpret_cast<const short8*>((pk0) + (mh) * 8192 + m_ * 1024); \
      Xf[1][m_] = *reinterpret_cast<const short8*>((pk1) + (mh) * 8192 + m_ * 1024); \
    } } while (0)

#define LDB(pk0, pk1, nh) do { \
    _Pragma("unroll") for (int n_ = 0; n_ < 2; ++n_) { \
      Bf[nh][0][n_] = *reinterpret_cast<const short8*>((pk0) + (nh) * 8192 + n_ * 1024); \
      Bf[nh][1][n_] = *reinterpret_cast<const short8*>((pk1) + (nh) * 8192 + n_ * 1024); \
    } } while (0)

#define MM4(mh, nh) do { \
    __builtin_amdgcn_s_setprio(1); \
    _Pragma("unroll") for (int ki_ = 0; ki_ < 2; ++ki_) \
    _Pragma("unroll") for (int m_ = 0; m_ < 4; ++m_) \
    _Pragma("unroll") for (int n_ = 0; n_ < 2; ++n_) \
      acc[(mh) * 4 + m_][(nh) * 2 + n_] = mm16<F16>( \
          Xf[ki_][m_], Bf[nh][ki_][n_], acc[(mh) * 4 + m_][(nh) * 2 + n_]); \
    __builtin_amdgcn_s_setprio(0); \
  } while (0)

template <int KDIM, bool F16>
__device__ __forceinline__ void gemm_core(
    const unsigned short* __restrict__ Amat, int m0,
    const unsigned short* __restrict__ Bmat, int n0,
    unsigned short* smem, f32x4 (&acc)[8][4], const int tid) {
  static_assert(KDIM % 128 == 0 && KDIM >= 256, "KDIM");
  const int lane = tid & 63, w = tid >> 6;
  const int wr = w >> 2, wc = w & 3;
  const int cl = lane & 15, kg = lane >> 4;
  unsigned short* const A0b = smem;
  unsigned short* const B0b = smem + 16384;
  unsigned short* const A1b = smem + 32768;
  unsigned short* const B1b = smem + 49152;
  // staging geometry: call c covers rows c*64 + (tid>>3), chunk slot tid&7;
  // source chunk = slot ^ (row&7); (c*64)&7==0 so the XOR is c-invariant.
  const int srow = tid >> 3;
  const int tcs = (tid & 7) ^ (srow & 7);
  const unsigned short* aS = Amat + (size_t)(m0 + srow) * KDIM + tcs * 8;
  const unsigned short* bS = Bmat + (size_t)(n0 + srow) * KDIM + tcs * 8;

  // frag-read swizzle constants: row&7 == cl&7 for all frag rows, so the
  // chunk index is lane-constant: cc = (ki*4+kg)^(cl&7); ki flips ^32 shorts.
  const int cc0 = kg ^ (cl & 7);
  const int oA0 = (wr * 64 + cl) * 64 + cc0 * 8;
  const int oA1 = oA0 ^ 32;
  const int oB0 = (wc * 32 + cl) * 64 + cc0 * 8;
  const int oB1 = oB0 ^ 32;
  const unsigned short* const pA0k0 = A0b + oA0;
  const unsigned short* const pA0k1 = A0b + oA1;
  const unsigned short* const pA1k0 = A1b + oA0;
  const unsigned short* const pA1k1 = A1b + oA1;
  const unsigned short* const pB0k0 = B0b + oB0;
  const unsigned short* const pB0k1 = B0b + oB1;
  const unsigned short* const pB1k0 = B1b + oB0;
  const unsigned short* const pB1k1 = B1b + oB1;

  short8 Xf[2][4], Bf[2][2][2];

  // prologue: t0 full (8) + t1 sans A-h1 (6) = 14 loads; wait all but t1's 6
  SCA(A0b, 0, 0); SCA(A0b, 1, 0);
  SCB(B0b, 0, 0); SCB(B0b, 1, 0);
  SCB(B0b, 2, 0); SCB(B0b, 3, 0);
  SCA(A0b, 2, 0); SCA(A0b, 3, 0);
  SCA(A1b, 0, 64); SCA(A1b, 1, 64);
  SCB(B1b, 0, 64); SCB(B1b, 1, 64);
  SCB(B1b, 2, 64); SCB(B1b, 3, 64);
  GVMC(6);
  GBAR();
  LDX(pA0k0, pA0k1, 0);  // X0(t0)
  LDB(pB0k0, pB0k1, 0);  // B0(t0)

  constexpr int G = KDIM / 128;  // groups of 2 K-tiles
#pragma unroll 1
  for (int g = 0; g < G - 1; ++g) {
    const int kA = g * 128 + 64;   // t1 = 2g+1 (buf1): A-h1 staged ph1
    const int kB = g * 128 + 128;  // t2 = 2g+2 (buf0): staged ph2-5
    const int kC = g * 128 + 192;  // t3 = 2g+3 (buf1): 3 halves, ph6-8
    // ph1: MM(0,0)=X0*B0; read B1 (for ph2)
    SCA(A1b, 2, kA); SCA(A1b, 3, kA);
    LDB(pB0k0, pB0k1, 1);
    MM4(0, 0);
    GBAR();
    // ph2: MM(0,1)=X0*B1; post-MM read X1 (SSA: MM reads old Xf)
    SCA(A0b, 0, kB); SCA(A0b, 1, kB);
    MM4(0, 1);
    LDX(pA0k0, pA0k1, 1);
    GBAR();
    // ph3: MM(1,0)=X1*B0
    SCB(B0b, 0, kB); SCB(B0b, 1, kB);
    MM4(1, 0);
    GBAR();
    // ph4: MM(1,1)=X1*B1 first; then vmc6+BAR (t1 resident all-waves);
    // then read X0',B0' (drain under ph5's MM issue).
    SCB(B0b, 2, kB); SCB(B0b, 3, kB);
    MM4(1, 1);
    GVMC(6);
    GBAR();
    LDX(pA1k0, pA1k1, 0);
    LDB(pB1k0, pB1k1, 0);
    GBAR();
    // ph5: MM(0,0)'=X0'*B0'; read B1'
    SCA(A0b, 2, kB); SCA(A0b, 3, kB);
    LDB(pB1k0, pB1k1, 1);
    MM4(0, 0);
    GBAR();
    // ph6: MM(0,1)'=X0'*B1'; post-MM read X1'
    SCA(A1b, 0, kC); SCA(A1b, 1, kC);
    MM4(0, 1);
    LDX(pA1k0, pA1k1, 1);
    GBAR();
    // ph7: MM(1,0)'=X1'*B0'
    SCB(B1b, 0, kC); SCB(B1b, 1, kC);
    MM4(1, 0);
    GBAR();
    // ph8: MM(1,1)'=X1'*B1' first; vmc6+BAR (t2 resident); read X0'',B0''
    SCB(B1b, 2, kC); SCB(B1b, 3, kC);
    MM4(1, 1);
    GVMC(6);
    GBAR();
    LDX(pA0k0, pA0k1, 0);
    LDB(pB0k0, pB0k1, 0);
    GBAR();
  }
  // tail group: t_{2G-2}(buf0), t_{2G-1}(buf1); only t_{2G-1} A-h1 to stage
  {
    const int kA = KDIM - 64;
    SCA(A1b, 2, kA); SCA(A1b, 3, kA);
    LDB(pB0k0, pB0k1, 1);
    MM4(0, 0);
    GBAR();
    MM4(0, 1);
    LDX(pA0k0, pA0k1, 1);
    GBAR();
    MM4(1, 0);
    GBAR();
    MM4(1, 1);
    GVMC(0);
    GBAR();
    LDX(pA1k0, pA1k1, 0);
    LDB(pB1k0, pB1k1, 0);
    GBAR();
    LDB(pB1k0, pB1k1, 1);
    MM4(0, 0);
    GBAR();
    MM4(0, 1);
    LDX(pA1k0, pA1k1, 1);
    GBAR();
    MM4(1, 0);
    GBAR();
    MM4(1, 1);
  }
}

// ---- GEMM1: f16 chain, 256^2 8-phase core + quantize/flag/flush epilogue --
__global__ __launch_bounds__(512, 2) void gemm1_k(
    const unsigned short* __restrict__ xh, const unsigned short* __restrict__ ah,
    unsigned short* __restrict__ kb2, unsigned int* __restrict__ counts,
    unsigned int* __restrict__ lists) {
  __shared__ __align__(128) unsigned short smem[65536];  // 128 KB
  __shared__ unsigned int lmeta[2050];

  const int tid = threadIdx.x, lane = tid & 63, w = tid >> 6;
  const int wr = w >> 2, wc = w & 3;
  const int cl = lane & 15, kg = lane >> 4;
  // XCD-bijective swizzle (m204; nwg=512, nwg%8==0, q=64)
  const int orig = blockIdx.y * 8 + blockIdx.x;
  const int swz = (orig & 7) * 64 + (orig >> 3);
  const int m0 = (swz >> 3) * 256, n0 = (swz & 7) * 256;
  const int bt = m0 >> 8;  // 256-row slab index 0..63

  f32x4 acc[8][4];
#pragma unroll
  for (int m = 0; m < 8; ++m)
#pragma unroll
    for (int n = 0; n < 4; ++n)
#pragma unroll
      for (int q = 0; q < 4; ++q) acc[m][n][q] = 0.0f;

  if (tid == 0) lmeta[0] = 0;  // published by core's prologue barrier

  gemm_core<D_DIM, true>(xh, m0, ah, n0, smem, acc, tid);

  // ---- epilogue: quantize -> bf16 2k in LDS (XOR-swz), flags, flush ------
  __syncthreads();
  unsigned short* sq = smem;  // [256][256] bf16, chunk-swizzled
  unsigned int* mylist = lists + (size_t)bt * TILE_CAP;
#pragma unroll
  for (int mi = 0; mi < 8; ++mi)
#pragma unroll
    for (int ni = 0; ni < 4; ++ni) {
      const int rowb = (mi >> 2) * 128 + wr * 64 + (mi & 3) * 16 + kg * 4;
      const int col = (ni >> 1) * 128 + wc * 32 + (ni & 1) * 16 + cl;
#pragma unroll
      for (int reg = 0; reg < 4; ++reg) {
        const int row = rowb + reg;
        const float kr = acc[mi][ni][reg] * 20.0f;
        const float rr = rintf(kr);
        if (0.5f - fabsf(kr - rr) < 2e-3f) {  // r7-r26-validated window
          const unsigned int code =
              ((unsigned int)(m0 + row) << 11) | (unsigned int)(n0 + col);
          const unsigned int li = atomicAdd(&lmeta[0], 1u);  // LDS atomic
          if (li < LCAP) lmeta[1 + li] = code;
          else {
            const unsigned int gi = atomicAdd(&counts[bt], 1u);
            if (gi < TILE_CAP) mylist[gi] = code;
          }
        }
        // swizzled store: chunk (col>>3) with low 3 bits XOR (row&7)
        const int ch = col >> 3;
        const int csw = (ch & 24) | ((ch & 7) ^ (row & 7));
        sq[row * 256 + csw * 8 + (col & 7)] =
            bf16_rne((float)(2 * (int)rr));  // exact
      }
    }
  __syncthreads();
  if (tid == 0) {
    const unsigned int c = lmeta[0] < LCAP ? lmeta[0] : LCAP;
    lmeta[2049] = atomicAdd(&counts[bt], c);  // ONE global atomic per block
  }
  __syncthreads();
  {
    const unsigned int c = lmeta[0] < LCAP ? lmeta[0] : LCAP;
    const unsigned int base = lmeta[2049];
    for (unsigned int t = tid; t < c; t += 512)
      if (base + t < TILE_CAP) mylist[base + t] = lmeta[1 + t];
  }
  {
    const int row = tid >> 1, half = tid & 1;
    unsigned short* dst = kb2 + (size_t)(m0 + row) * A_ROWS + n0 + half * 128;
#pragma unroll
    for (int j = 0; j < 16; ++j) {
      const int creal = half * 16 + j;
      const int csw = (creal & 24) | ((creal & 7) ^ (row & 7));
      reinterpret_cast<int4*>(dst)[j] =
          *reinterpret_cast<const int4*>(sq + row * 256 + csw * 8);
    }
  }
}

// ---- fixup: wave-per-flag, 2-deep pipelined gather, bucketed by slab ------
__global__ __launch_bounds__(256) void fixup_k(
    const float* __restrict__ x, const float* __restrict__ anc,
    const double* __restrict__ inv_norms, const unsigned int* __restrict__ counts,
    const unsigned int* __restrict__ lists, unsigned short* __restrict__ kb2) {
  const int bt = blockIdx.x & 63;
  const int sub = blockIdx.x >> 6;          // 0..127
  unsigned int cnt = counts[bt];
  if (cnt > TILE_CAP) cnt = TILE_CAP;
  const unsigned int* mylist = lists + (size_t)bt * TILE_CAP;
  const int lane = threadIdx.x & 63;
  const int wib = threadIdx.x >> 6;         // wave in block 0..3
  unsigned int i = (unsigned int)(sub * 4 + wib);
  if (i >= cnt) return;
  const unsigned int stride = 512;          // 128 subs x 4 waves

  unsigned int code = mylist[i];
  float4 xc0, xc1, xc2, xc3, ac0, ac1, ac2, ac3;
  {
    const int b = code >> 11, a = code & 2047;
    const float4* xp = reinterpret_cast<const float4*>(x + (size_t)b * D_DIM) + lane;
    const float4* ap = reinterpret_cast<const float4*>(anc + (size_t)a * D_DIM) + lane;
    xc0 = xp[0]; xc1 = xp[64]; xc2 = xp[128]; xc3 = xp[192];
    ac0 = ap[0]; ac1 = ap[64]; ac2 = ap[128]; ac3 = ap[192];
  }
  for (;;) {
    const unsigned int inext = i + stride;
    const bool have = inext < cnt;
    unsigned int coden = 0;
    float4 xn0, xn1, xn2, xn3, an0, an1, an2, an3;
    if (have) {  // issue next flag's gather (hides under current compute)
      coden = mylist[inext];
      const int b = coden >> 11, a = coden & 2047;
      const float4* xp = reinterpret_cast<const float4*>(x + (size_t)b * D_DIM) + lane;
      const float4* ap = reinterpret_cast<const float4*>(anc + (size_t)a * D_DIM) + lane;
      xn0 = xp[0]; xn1 = xp[64]; xn2 = xp[128]; xn3 = xp[192];
      an0 = ap[0]; an1 = ap[64]; an2 = ap[128]; an3 = ap[192];
    }
    {
      double p0 = (double)xc0.x * (double)ac0.x + (double)xc0.y * (double)ac0.y +
                  (double)xc0.z * (double)ac0.z + (double)xc0.w * (double)ac0.w;
      double p1 = (double)xc1.x * (double)ac1.x + (double)xc1.y * (double)ac1.y +
                  (double)xc1.z * (double)ac1.z + (double)xc1.w * (double)ac1.w;
      double p2 = (double)xc2.x * (double)ac2.x + (double)xc2.y * (double)ac2.y +
                  (double)xc2.z * (double)ac2.z + (double)xc2.w * (double)ac2.w;
      double p3 = (double)xc3.x * (double)ac3.x + (double)xc3.y * (double)ac3.y +
                  (double)xc3.z * (double)ac3.z + (double)xc3.w * (double)ac3.w;
      double s = (p0 + p1) + (p2 + p3);
      s += __shfl_xor(s, 32);
      s += __shfl_xor(s, 16);
      s += __shfl_xor(s, 8);
      s += __shfl_xor(s, 4);
      s += __shfl_xor(s, 2);
      s += __shfl_xor(s, 1);
      if (lane == 0) {
        const int b = code >> 11, a = code & 2047;
        const double sim = s * inv_norms[b] * inv_norms[B_ROWS + a];
        const double kr = sim / 0.05;
        const double r = rint(kr);
        const double fr = kr - r;
        int k2 = 2 * (int)r;
        if (0.5 - fabs(fr) < 2.5e-6) k2 += (fr > 0.0) ? 1 : -1;  // midpoint hedge
        kb2[(size_t)b * A_ROWS + a] = bf16_rne((float)k2);       // exact int
      }
    }
    if (!have) break;
    i = inext; code = coden;
    xc0 = xn0; xc1 = xn1; xc2 = xn2; xc3 = xn3;
    ac0 = an0; ac1 = an1; ac2 = an2; ac3 = an3;
  }
}

// ---- GEMM2: bf16 chain, K=2048, 256^2 8-phase core, out = .025*k2@vbT -----
__global__ __launch_bounds__(512, 2) void gemm2_k(
    const unsigned short* __restrict__ kb2, const unsigned short* __restrict__ vbT,
    float* __restrict__ out) {
  __shared__ __align__(128) unsigned short smem[65536];  // 128 KB

  const int tid = threadIdx.x, lane = tid & 63, w = tid >> 6;
  const int wr = w >> 2, wc = w & 3;
  const int cl = lane & 15, kg = lane >> 4;
  // XCD-bijective swizzle (nwg=256, q=32)
  const int orig = blockIdx.y * 4 + blockIdx.x;
  const int swz = (orig & 7) * 32 + (orig >> 3);
  const int m0 = (swz >> 2) * 256, h0 = (swz & 3) * 256;

  f32x4 acc[8][4];
#pragma unroll
  for (int m = 0; m < 8; ++m)
#pragma unroll
    for (int n = 0; n < 4; ++n)
#pragma unroll
      for (int q = 0; q < 4; ++q) acc[m][n][q] = 0.0f;

  gemm_core<A_ROWS, false>(kb2, m0, vbT, h0, smem, acc, tid);

#pragma unroll
  for (int mi = 0; mi < 8; ++mi)
#pragma unroll
    for (int ni = 0; ni < 4; ++ni) {
      const int rowb = (mi >> 2) * 128 + wr * 64 + (mi & 3) * 16 + kg * 4;
      const int col = (ni >> 1) * 128 + wc * 32 + (ni & 1) * 16 + cl;
#pragma unroll
      for (int reg = 0; reg < 4; ++reg)
        out[(size_t)(m0 + rowb + reg) * H_DIM + h0 + col] =
            0.025f * acc[mi][ni][reg];
    }
}

// ---------------------------------------------------------------------------
extern "C" void kernel_launch(void* const* d_in, const int* in_sizes, int n_in,
                              void* d_out, int out_size, void* d_ws, size_t ws_size,
                              hipStream_t stream) {
  const float* x      = (const float*)d_in[0];
  const float* anc    = (const float*)d_in[1];
  const float* values = (const float*)d_in[2];
  float* out = (float*)d_out;

  char* ws = (char*)d_ws;
  double* inv_norms    = (double*)(ws);
  unsigned int* counts = (unsigned int*)(ws + 0x24000);
  unsigned int* lists  = (unsigned int*)(ws + 0x24200);
  unsigned short* xh   = (unsigned short*)(ws + 0x324000);
  unsigned short* ah   = (unsigned short*)(ws + 0x2324000);
  unsigned short* vbT  = (unsigned short*)(ws + 0x2724000);
  unsigned short* kb2  = (unsigned short*)(ws + 0x2B24000);

  prep_k<<<B_ROWS + A_ROWS + (H_DIM / 16) * (A_ROWS / 16), 256, 0, stream>>>(
      x, anc, values, inv_norms, xh, ah, vbT, counts);
  gemm1_k<<<dim3(A_ROWS / 256, B_ROWS / 256), 512, 0, stream>>>(xh, ah, kb2, counts, lists);
  fixup_k<<<8192, 256, 0, stream>>>(x, anc, inv_norms, counts, lists, kb2);
  gemm2_k<<<dim3(H_DIM / 256, B_ROWS / 256), 512, 0, stream>>>(kb2, vbT, out);
}

// Round 11
// 275.729 us; speedup vs baseline: 1.1090x; 1.0105x over previous
//
#include <hip/hip_runtime.h>
#include <math.h>

// RelativeAttention: out = round((x_n @ a_n^T)/0.05)*0.05 @ values
//
// Round 28 (from r27 WIN @ 278.6us): fixup TLP x2 (16384 blocks, stride
// 1024, ~2 flags/wave; 2-deep pipeline intact). Everything else identical
// to r27: merged prep (BW-saturated ~6.4TB/s), r24 GEMM core (six schedule
// variants 110-120us -> family closed; 32x32 = bank-conflict regression;
// 2x8-wave occupancy blocked by 256 regs/wave). absmax canary 2.685547e-3.
//
// ws layout (bytes):
//   [0x0,       0x24000)   inv_norms f64 (16384 x | 2048 anchors)
//   [0x24000,   0x24200)   counts u32[64] (128 slots reserved)
//   [0x24200,   0x224200)  lists u32[64][8192]
//   [0x324000,  0x2324000) xh f16 [16384][1024] (32MB)
//   [0x2324000, 0x2724000) ah f16 [2048][1024] (4MB)
//   [0x2724000, 0x2B24000) vbT bf16 [1024][2048] (values^T, 4MB)
//   [0x2B24000, 0x6B24000) kb2 bf16 [16384][2048] (2*bin, odd = midpoint)

#define B_ROWS 16384
#define A_ROWS 2048
#define D_DIM  1024
#define H_DIM  1024
#define TILE_CAP 8192u
#define LCAP 2040u

typedef __attribute__((ext_vector_type(8))) short short8;
typedef __attribute__((ext_vector_type(8))) _Float16 half8;
typedef __attribute__((ext_vector_type(4))) float f32x4;

__device__ inline unsigned short bf16_rne(float f) {
  unsigned int u = __float_as_uint(f);
  unsigned int r = (u + 0x7FFFu + ((u >> 16) & 1u)) >> 16;
  return (unsigned short)r;
}
__device__ inline unsigned short f16_bits(float f) {
  _Float16 h = (_Float16)f;
  return __builtin_bit_cast(unsigned short, h);
}
__device__ inline void gload16(const void* g, void* l) {
  __builtin_amdgcn_global_load_lds(
      (const __attribute__((address_space(1))) unsigned int*)g,
      (__attribute__((address_space(3))) unsigned int*)l, 16, 0, 0);
}

template <bool F16>
__device__ __forceinline__ f32x4 mm16(short8 a, short8 b, f32x4 c) {
  if constexpr (F16)
    return __builtin_amdgcn_mfma_f32_16x16x32_f16(
        __builtin_bit_cast(half8, a), __builtin_bit_cast(half8, b), c, 0, 0, 0);
  else
    return __builtin_amdgcn_mfma_f32_16x16x32_bf16(a, b, c, 0, 0, 0);
}

// ---- merged prep: norm+f16 (x rows | anchor rows) + values^T + zero cnts --
__global__ __launch_bounds__(256) void prep_k(
    const float* __restrict__ x, const float* __restrict__ anc,
    const float* __restrict__ values, double* __restrict__ inv_norms,
    unsigned short* __restrict__ xh, unsigned short* __restrict__ ah,
    unsigned short* __restrict__ vbT, unsigned int* __restrict__ counts) {
  const int blk = blockIdx.x;
  const int t = threadIdx.x;
  if (blk < B_ROWS + A_ROWS) {
    // ---- normprep branch (r3-proven f64 tree, fp-contract off) ----
#pragma clang fp contract(off)
    const bool isx = blk < B_ROWS;
    const int r = isx ? blk : blk - B_ROWS;
    const float* src = isx ? x + (size_t)r * D_DIM : anc + (size_t)r * D_DIM;
    double* inv_out = isx ? inv_norms + r : inv_norms + B_ROWS + r;
    unsigned short* dst = isx ? xh + (size_t)r * D_DIM : ah + (size_t)r * D_DIM;
    const float4 v = reinterpret_cast<const float4*>(src)[t];
    double s = (double)v.x * (double)v.x + (double)v.y * (double)v.y +
               (double)v.z * (double)v.z + (double)v.w * (double)v.w;
#pragma unroll
    for (int off = 32; off > 0; off >>= 1) s += __shfl_down(s, off);
    __shared__ double red[4];
    __shared__ double sinv;
    if ((t & 63) == 0) red[t >> 6] = s;
    __syncthreads();
    if (t == 0) {
      const double n = sqrt(red[0] + red[1] + red[2] + red[3]);
      const double inv = 1.0 / fmax(n, 1e-12);
      *inv_out = inv;
      sinv = inv;
    }
    __syncthreads();
    const float invn = (float)sinv;
    ushort4 o;
    o.x = f16_bits(v.x * invn); o.y = f16_bits(v.y * invn);
    o.z = f16_bits(v.z * invn); o.w = f16_bits(v.w * invn);
    reinterpret_cast<ushort4*>(dst)[t] = o;
  } else {
    // ---- prep_vt branch: 16x16 transpose tile (+ zero counts, tile 0) ----
    const int tile = blk - (B_ROWS + A_ROWS);
    const int tx = t & 15, ty = t >> 4;
    __shared__ float sm[16][17];
    if (tile == 0 && t < 128) counts[t] = 0;
    const int h0 = (tile & 63) * 16, a0 = (tile >> 6) * 16;
    sm[ty][tx] = values[(size_t)(a0 + ty) * H_DIM + h0 + tx];
    __syncthreads();
    vbT[(size_t)(h0 + ty) * A_ROWS + a0 + tx] = bf16_rne(sm[tx][ty]);
  }
}

// ------ 256x256 / BK=64 / 8-wave / 8-phase read-ahead GEMM core -----------
// LDS: buf0 {A:[256][64] @0, B @16384}, buf1 {A @32768, B @49152} (shorts).
// Chunk-XOR swizzle: row r's chunk k (16B) lives at slot k^(r&7); staging
// pre-swizzles the per-lane GLOBAL source so the LDS dest stays linear.
#define GBAR() do { __builtin_amdgcn_s_barrier(); \
                    asm volatile("" ::: "memory"); } while (0)
#define GVMC(n) asm volatile("s_waitcnt vmcnt(" #n ")" ::: "memory")

#define SCA(buf, c, kv) gload16(aS + (size_t)(c) * 64 * KDIM + (kv), \
                                (buf) + (c) * 4096 + tid * 8)
#define SCB(buf, c, kv) gload16(bS + (size_t)(c) * 64 * KDIM + (kv), \
                                (buf) + (c) * 4096 + tid * 8)

// frag reads: plain C++ short8 loads off precomputed swizzled bases;
// compiler inserts counted lgkmcnt and interleaves with MFMA.
#define LDX(pk0, pk1, mh) do { \
    _Pragma("unroll") for (int m_ = 0; m_ < 4; ++m_) { \
      Xf[0][m_] = *reinterpret_cast<const short8*>((pk0) + (mh) * 8192 + m_ * 1024); \
      Xf[1][m_] = *reinterpret_cast<const short8*>((pk1) + (mh) * 8192 + m_ * 1024); \
    } } while (0)

#define LDB(pk0, pk1, nh) do { \
    _Pragma("unroll") for (int n_ = 0; n_ < 2; ++n_) { \
      Bf[nh][0][n_] = *reinterpret_cast<const short8*>((pk0) + (nh) * 8192 + n_ * 1024); \
      Bf[nh][1][n_] = *reinterpret_cast<const short8*>((pk1) + (nh) * 8192 + n_ * 1024); \
    } } while (0)

#define MM4(mh, nh) do { \
    __builtin_amdgcn_s_setprio(1); \
    _Pragma("unroll") for (int ki_ = 0; ki_ < 2; ++ki_) \
    _Pragma("unroll") for (int m_ = 0; m_ < 4; ++m_) \
    _Pragma("unroll") for (int n_ = 0; n_ < 2; ++n_) \
      acc[(mh) * 4 + m_][(nh) * 2 + n_] = mm16<F16>( \
          Xf[ki_][m_], Bf[nh][ki_][n_], acc[(mh) * 4 + m_][(nh) * 2 + n_]); \
    __builtin_amdgcn_s_setprio(0); \
  } while (0)

template <int KDIM, bool F16>
__device__ __forceinline__ void gemm_core(
    const unsigned short* __restrict__ Amat, int m0,
    const unsigned short* __restrict__ Bmat, int n0,
    unsigned short* smem, f32x4 (&acc)[8][4], const int tid) {
  static_assert(KDIM % 128 == 0 && KDIM >= 256, "KDIM");
  const int lane = tid & 63, w = tid >> 6;
  const int wr = w >> 2, wc = w & 3;
  const int cl = lane & 15, kg = lane >> 4;
  unsigned short* const A0b = smem;
  unsigned short* const B0b = smem + 16384;
  unsigned short* const A1b = smem + 32768;
  unsigned short* const B1b = smem + 49152;
  // staging geometry: call c covers rows c*64 + (tid>>3), chunk slot tid&7;
  // source chunk = slot ^ (row&7); (c*64)&7==0 so the XOR is c-invariant.
  const int srow = tid >> 3;
  const int tcs = (tid & 7) ^ (srow & 7);
  const unsigned short* aS = Amat + (size_t)(m0 + srow) * KDIM + tcs * 8;
  const unsigned short* bS = Bmat + (size_t)(n0 + srow) * KDIM + tcs * 8;

  // frag-read swizzle constants: row&7 == cl&7 for all frag rows, so the
  // chunk index is lane-constant: cc = (ki*4+kg)^(cl&7); ki flips ^32 shorts.
  const int cc0 = kg ^ (cl & 7);
  const int oA0 = (wr * 64 + cl) * 64 + cc0 * 8;
  const int oA1 = oA0 ^ 32;
  const int oB0 = (wc * 32 + cl) * 64 + cc0 * 8;
  const int oB1 = oB0 ^ 32;
  const unsigned short* const pA0k0 = A0b + oA0;
  const unsigned short* const pA0k1 = A0b + oA1;
  const unsigned short* const pA1k0 = A1b + oA0;
  const unsigned short* const pA1k1 = A1b + oA1;
  const unsigned short* const pB0k0 = B0b + oB0;
  const unsigned short* const pB0k1 = B0b + oB1;
  const unsigned short* const pB1k0 = B1b + oB0;
  const unsigned short* const pB1k1 = B1b + oB1;

  short8 Xf[2][4], Bf[2][2][2];

  // prologue: t0 full (8) + t1 sans A-h1 (6) = 14 loads; wait all but t1's 6
  SCA(A0b, 0, 0); SCA(A0b, 1, 0);
  SCB(B0b, 0, 0); SCB(B0b, 1, 0);
  SCB(B0b, 2, 0); SCB(B0b, 3, 0);
  SCA(A0b, 2, 0); SCA(A0b, 3, 0);
  SCA(A1b, 0, 64); SCA(A1b, 1, 64);
  SCB(B1b, 0, 64); SCB(B1b, 1, 64);
  SCB(B1b, 2, 64); SCB(B1b, 3, 64);
  GVMC(6);
  GBAR();
  LDX(pA0k0, pA0k1, 0);  // X0(t0)
  LDB(pB0k0, pB0k1, 0);  // B0(t0)

  constexpr int G = KDIM / 128;  // groups of 2 K-tiles
#pragma unroll 1
  for (int g = 0; g < G - 1; ++g) {
    const int kA = g * 128 + 64;   // t1 = 2g+1 (buf1): A-h1 staged ph1
    const int kB = g * 128 + 128;  // t2 = 2g+2 (buf0): staged ph2-5
    const int kC = g * 128 + 192;  // t3 = 2g+3 (buf1): 3 halves, ph6-8
    // ph1: MM(0,0)=X0*B0; read B1 (for ph2)
    SCA(A1b, 2, kA); SCA(A1b, 3, kA);
    LDB(pB0k0, pB0k1, 1);
    MM4(0, 0);
    GBAR();
    // ph2: MM(0,1)=X0*B1; post-MM read X1 (SSA: MM reads old Xf)
    SCA(A0b, 0, kB); SCA(A0b, 1, kB);
    MM4(0, 1);
    LDX(pA0k0, pA0k1, 1);
    GBAR();
    // ph3: MM(1,0)=X1*B0
    SCB(B0b, 0, kB); SCB(B0b, 1, kB);
    MM4(1, 0);
    GBAR();
    // ph4: MM(1,1)=X1*B1 first; then vmc6+BAR (t1 resident all-waves);
    // then read X0',B0' (drain under ph5's MM issue).
    SCB(B0b, 2, kB); SCB(B0b, 3, kB);
    MM4(1, 1);
    GVMC(6);
    GBAR();
    LDX(pA1k0, pA1k1, 0);
    LDB(pB1k0, pB1k1, 0);
    GBAR();
    // ph5: MM(0,0)'=X0'*B0'; read B1'
    SCA(A0b, 2, kB); SCA(A0b, 3, kB);
    LDB(pB1k0, pB1k1, 1);
    MM4(0, 0);
    GBAR();
    // ph6: MM(0,1)'=X0'*B1'; post-MM read X1'
    SCA(A1b, 0, kC); SCA(A1b, 1, kC);
    MM4(0, 1);
    LDX(pA1k0, pA1k1, 1);
    GBAR();
    // ph7: MM(1,0)'=X1'*B0'
    SCB(B1b, 0, kC); SCB(B1b, 1, kC);
    MM4(1, 0);
    GBAR();
    // ph8: MM(1,1)'=X1'*B1' first; vmc6+BAR (t2 resident); read X0'',B0''
    SCB(B1b, 2, kC); SCB(B1b, 3, kC);
    MM4(1, 1);
    GVMC(6);
    GBAR();
    LDX(pA0k0, pA0k1, 0);
    LDB(pB0k0, pB0k1, 0);
    GBAR();
  }
  // tail group: t_{2G-2}(buf0), t_{2G-1}(buf1); only t_{2G-1} A-h1 to stage
  {
    const int kA = KDIM - 64;
    SCA(A1b, 2, kA); SCA(A1b, 3, kA);
    LDB(pB0k0, pB0k1, 1);
    MM4(0, 0);
    GBAR();
    MM4(0, 1);
    LDX(pA0k0, pA0k1, 1);
    GBAR();
    MM4(1, 0);
    GBAR();
    MM4(1, 1);
    GVMC(0);
    GBAR();
    LDX(pA1k0, pA1k1, 0);
    LDB(pB1k0, pB1k1, 0);
    GBAR();
    LDB(pB1k0, pB1k1, 1);
    MM4(0, 0);
    GBAR();
    MM4(0, 1);
    LDX(pA1k0, pA1k1, 1);
    GBAR();
    MM4(1, 0);
    GBAR();
    MM4(1, 1);
  }
}

// ---- GEMM1: f16 chain, 256^2 8-phase core + quantize/flag/flush epilogue --
__global__ __launch_bounds__(512, 2) void gemm1_k(
    const unsigned short* __restrict__ xh, const unsigned short* __restrict__ ah,
    unsigned short* __restrict__ kb2, unsigned int* __restrict__ counts,
    unsigned int* __restrict__ lists) {
  __shared__ __align__(128) unsigned short smem[65536];  // 128 KB
  __shared__ unsigned int lmeta[2050];

  const int tid = threadIdx.x, lane = tid & 63, w = tid >> 6;
  const int wr = w >> 2, wc = w & 3;
  const int cl = lane & 15, kg = lane >> 4;
  // XCD-bijective swizzle (m204; nwg=512, nwg%8==0, q=64)
  const int orig = blockIdx.y * 8 + blockIdx.x;
  const int swz = (orig & 7) * 64 + (orig >> 3);
  const int m0 = (swz >> 3) * 256, n0 = (swz & 7) * 256;
  const int bt = m0 >> 8;  // 256-row slab index 0..63

  f32x4 acc[8][4];
#pragma unroll
  for (int m = 0; m < 8; ++m)
#pragma unroll
    for (int n = 0; n < 4; ++n)
#pragma unroll
      for (int q = 0; q < 4; ++q) acc[m][n][q] = 0.0f;

  if (tid == 0) lmeta[0] = 0;  // published by core's prologue barrier

  gemm_core<D_DIM, true>(xh, m0, ah, n0, smem, acc, tid);

  // ---- epilogue: quantize -> bf16 2k in LDS (XOR-swz), flags, flush ------
  __syncthreads();
  unsigned short* sq = smem;  // [256][256] bf16, chunk-swizzled
  unsigned int* mylist = lists + (size_t)bt * TILE_CAP;
#pragma unroll
  for (int mi = 0; mi < 8; ++mi)
#pragma unroll
    for (int ni = 0; ni < 4; ++ni) {
      const int rowb = (mi >> 2) * 128 + wr * 64 + (mi & 3) * 16 + kg * 4;
      const int col = (ni >> 1) * 128 + wc * 32 + (ni & 1) * 16 + cl;
#pragma unroll
      for (int reg = 0; reg < 4; ++reg) {
        const int row = rowb + reg;
        const float kr = acc[mi][ni][reg] * 20.0f;
        const float rr = rintf(kr);
        if (0.5f - fabsf(kr - rr) < 2e-3f) {  // r7-r27-validated window
          const unsigned int code =
              ((unsigned int)(m0 + row) << 11) | (unsigned int)(n0 + col);
          const unsigned int li = atomicAdd(&lmeta[0], 1u);  // LDS atomic
          if (li < LCAP) lmeta[1 + li] = code;
          else {
            const unsigned int gi = atomicAdd(&counts[bt], 1u);
            if (gi < TILE_CAP) mylist[gi] = code;
          }
        }
        // swizzled store: chunk (col>>3) with low 3 bits XOR (row&7)
        const int ch = col >> 3;
        const int csw = (ch & 24) | ((ch & 7) ^ (row & 7));
        sq[row * 256 + csw * 8 + (col & 7)] =
            bf16_rne((float)(2 * (int)rr));  // exact
      }
    }
  __syncthreads();
  if (tid == 0) {
    const unsigned int c = lmeta[0] < LCAP ? lmeta[0] : LCAP;
    lmeta[2049] = atomicAdd(&counts[bt], c);  // ONE global atomic per block
  }
  __syncthreads();
  {
    const unsigned int c = lmeta[0] < LCAP ? lmeta[0] : LCAP;
    const unsigned int base = lmeta[2049];
    for (unsigned int t = tid; t < c; t += 512)
      if (base + t < TILE_CAP) mylist[base + t] = lmeta[1 + t];
  }
  {
    const int row = tid >> 1, half = tid & 1;
    unsigned short* dst = kb2 + (size_t)(m0 + row) * A_ROWS + n0 + half * 128;
#pragma unroll
    for (int j = 0; j < 16; ++j) {
      const int creal = half * 16 + j;
      const int csw = (creal & 24) | ((creal & 7) ^ (row & 7));
      reinterpret_cast<int4*>(dst)[j] =
          *reinterpret_cast<const int4*>(sq + row * 256 + csw * 8);
    }
  }
}

// ---- fixup: wave-per-flag, 2-deep pipelined gather, bucketed by slab ------
__global__ __launch_bounds__(256) void fixup_k(
    const float* __restrict__ x, const float* __restrict__ anc,
    const double* __restrict__ inv_norms, const unsigned int* __restrict__ counts,
    const unsigned int* __restrict__ lists, unsigned short* __restrict__ kb2) {
  const int bt = blockIdx.x & 63;
  const int sub = blockIdx.x >> 6;          // 0..255
  unsigned int cnt = counts[bt];
  if (cnt > TILE_CAP) cnt = TILE_CAP;
  const unsigned int* mylist = lists + (size_t)bt * TILE_CAP;
  const int lane = threadIdx.x & 63;
  const int wib = threadIdx.x >> 6;         // wave in block 0..3
  unsigned int i = (unsigned int)(sub * 4 + wib);
  if (i >= cnt) return;
  const unsigned int stride = 1024;         // 256 subs x 4 waves

  unsigned int code = mylist[i];
  float4 xc0, xc1, xc2, xc3, ac0, ac1, ac2, ac3;
  {
    const int b = code >> 11, a = code & 2047;
    const float4* xp = reinterpret_cast<const float4*>(x + (size_t)b * D_DIM) + lane;
    const float4* ap = reinterpret_cast<const float4*>(anc + (size_t)a * D_DIM) + lane;
    xc0 = xp[0]; xc1 = xp[64]; xc2 = xp[128]; xc3 = xp[192];
    ac0 = ap[0]; ac1 = ap[64]; ac2 = ap[128]; ac3 = ap[192];
  }
  for (;;) {
    const unsigned int inext = i + stride;
    const bool have = inext < cnt;
    unsigned int coden = 0;
    float4 xn0, xn1, xn2, xn3, an0, an1, an2, an3;
    if (have) {  // issue next flag's gather (hides under current compute)
      coden = mylist[inext];
      const int b = coden >> 11, a = coden & 2047;
      const float4* xp = reinterpret_cast<const float4*>(x + (size_t)b * D_DIM) + lane;
      const float4* ap = reinterpret_cast<const float4*>(anc + (size_t)a * D_DIM) + lane;
      xn0 = xp[0]; xn1 = xp[64]; xn2 = xp[128]; xn3 = xp[192];
      an0 = ap[0]; an1 = ap[64]; an2 = ap[128]; an3 = ap[192];
    }
    {
      double p0 = (double)xc0.x * (double)ac0.x + (double)xc0.y * (double)ac0.y +
                  (double)xc0.z * (double)ac0.z + (double)xc0.w * (double)ac0.w;
      double p1 = (double)xc1.x * (double)ac1.x + (double)xc1.y * (double)ac1.y +
                  (double)xc1.z * (double)ac1.z + (double)xc1.w * (double)ac1.w;
      double p2 = (double)xc2.x * (double)ac2.x + (double)xc2.y * (double)ac2.y +
                  (double)xc2.z * (double)ac2.z + (double)xc2.w * (double)ac2.w;
      double p3 = (double)xc3.x * (double)ac3.x + (double)xc3.y * (double)ac3.y +
                  (double)xc3.z * (double)ac3.z + (double)xc3.w * (double)ac3.w;
      double s = (p0 + p1) + (p2 + p3);
      s += __shfl_xor(s, 32);
      s += __shfl_xor(s, 16);
      s += __shfl_xor(s, 8);
      s += __shfl_xor(s, 4);
      s += __shfl_xor(s, 2);
      s += __shfl_xor(s, 1);
      if (lane == 0) {
        const int b = code >> 11, a = code & 2047;
        const double sim = s * inv_norms[b] * inv_norms[B_ROWS + a];
        const double kr = sim / 0.05;
        const double r = rint(kr);
        const double fr = kr - r;
        int k2 = 2 * (int)r;
        if (0.5 - fabs(fr) < 2.5e-6) k2 += (fr > 0.0) ? 1 : -1;  // midpoint hedge
        kb2[(size_t)b * A_ROWS + a] = bf16_rne((float)k2);       // exact int
      }
    }
    if (!have) break;
    i = inext; code = coden;
    xc0 = xn0; xc1 = xn1; xc2 = xn2; xc3 = xn3;
    ac0 = an0; ac1 = an1; ac2 = an2; ac3 = an3;
  }
}

// ---- GEMM2: bf16 chain, K=2048, 256^2 8-phase core, out = .025*k2@vbT -----
__global__ __launch_bounds__(512, 2) void gemm2_k(
    const unsigned short* __restrict__ kb2, const unsigned short* __restrict__ vbT,
    float* __restrict__ out) {
  __shared__ __align__(128) unsigned short smem[65536];  // 128 KB

  const int tid = threadIdx.x, lane = tid & 63, w = tid >> 6;
  const int wr = w >> 2, wc = w & 3;
  const int cl = lane & 15, kg = lane >> 4;
  // XCD-bijective swizzle (nwg=256, q=32)
  const int orig = blockIdx.y * 4 + blockIdx.x;
  const int swz = (orig & 7) * 32 + (orig >> 3);
  const int m0 = (swz >> 2) * 256, h0 = (swz & 3) * 256;

  f32x4 acc[8][4];
#pragma unroll
  for (int m = 0; m < 8; ++m)
#pragma unroll
    for (int n = 0; n < 4; ++n)
#pragma unroll
      for (int q = 0; q < 4; ++q) acc[m][n][q] = 0.0f;

  gemm_core<A_ROWS, false>(kb2, m0, vbT, h0, smem, acc, tid);

#pragma unroll
  for (int mi = 0; mi < 8; ++mi)
#pragma unroll
    for (int ni = 0; ni < 4; ++ni) {
      const int rowb = (mi >> 2) * 128 + wr * 64 + (mi & 3) * 16 + kg * 4;
      const int col = (ni >> 1) * 128 + wc * 32 + (ni & 1) * 16 + cl;
#pragma unroll
      for (int reg = 0; reg < 4; ++reg)
        out[(size_t)(m0 + rowb + reg) * H_DIM + h0 + col] =
            0.025f * acc[mi][ni][reg];
    }
}

// ---------------------------------------------------------------------------
extern "C" void kernel_launch(void* const* d_in, const int* in_sizes, int n_in,
                              void* d_out, int out_size, void* d_ws, size_t ws_size,
                              hipStream_t stream) {
  const float* x      = (const float*)d_in[0];
  const float* anc    = (const float*)d_in[1];
  const float* values = (const float*)d_in[2];
  float* out = (float*)d_out;

  char* ws = (char*)d_ws;
  double* inv_norms    = (double*)(ws);
  unsigned int* counts = (unsigned int*)(ws + 0x24000);
  unsigned int* lists  = (unsigned int*)(ws + 0x24200);
  unsigned short* xh   = (unsigned short*)(ws + 0x324000);
  unsigned short* ah   = (unsigned short*)(ws + 0x2324000);
  unsigned short* vbT  = (unsigned short*)(ws + 0x2724000);
  unsigned short* kb2  = (unsigned short*)(ws + 0x2B24000);

  prep_k<<<B_ROWS + A_ROWS + (H_DIM / 16) * (A_ROWS / 16), 256, 0, stream>>>(
      x, anc, values, inv_norms, xh, ah, vbT, counts);
  gemm1_k<<<dim3(A_ROWS / 256, B_ROWS / 256), 512, 0, stream>>>(xh, ah, kb2, counts, lists);
  fixup_k<<<16384, 256, 0, stream>>>(x, anc, inv_norms, counts, lists, kb2);
  gemm2_k<<<dim3(H_DIM / 256, B_ROWS / 256), 512, 0, stream>>>(kb2, vbT, out);
}

// Round 12
// 263.990 us; speedup vs baseline: 1.1584x; 1.0445x over previous
//
#include <hip/hip_runtime.h>
#include <math.h>

// RelativeAttention: out = round((x_n @ a_n^T)/0.05)*0.05 @ values
//
// Round 29 (from r28 WIN @ 275.7us): FUSE fixup into gemm1's epilogue.
// Every flag (b,a) lies inside the tile of the block that produced it
// (expected ~262 flags/block, LCAP=2040 = ~100 sigma headroom), so after
// the quantize/flag pass the block's 8 waves split the LDS flag list
// (stride 8, r24-proven 2-deep pipelined gather, IDENTICAL f64 dot +
// 64-lane reduce + midpoint hedge -> bit-identical decisions) and lane 0
// writes the corrected bf16 into sq (LDS) BEFORE the single kb2 flush.
// Deleted: fixup kernel + launch gap, global lists/counts, list flush,
// counts zeroing in prep. Cores/prep otherwise byte-identical to r28
// (absmax canary 2.685547e-3).
//
// ws layout (bytes):
//   [0x0,       0x24000)   inv_norms f64 (16384 x | 2048 anchors)
//   [0x324000,  0x2324000) xh f16 [16384][1024] (32MB)
//   [0x2324000, 0x2724000) ah f16 [2048][1024] (4MB)
//   [0x2724000, 0x2B24000) vbT bf16 [1024][2048] (values^T, 4MB)
//   [0x2B24000, 0x6B24000) kb2 bf16 [16384][2048] (2*bin, odd = midpoint)

#define B_ROWS 16384
#define A_ROWS 2048
#define D_DIM  1024
#define H_DIM  1024
#define LCAP 2040u

typedef __attribute__((ext_vector_type(8))) short short8;
typedef __attribute__((ext_vector_type(8))) _Float16 half8;
typedef __attribute__((ext_vector_type(4))) float f32x4;

__device__ inline unsigned short bf16_rne(float f) {
  unsigned int u = __float_as_uint(f);
  unsigned int r = (u + 0x7FFFu + ((u >> 16) & 1u)) >> 16;
  return (unsigned short)r;
}
__device__ inline unsigned short f16_bits(float f) {
  _Float16 h = (_Float16)f;
  return __builtin_bit_cast(unsigned short, h);
}
__device__ inline void gload16(const void* g, void* l) {
  __builtin_amdgcn_global_load_lds(
      (const __attribute__((address_space(1))) unsigned int*)g,
      (__attribute__((address_space(3))) unsigned int*)l, 16, 0, 0);
}

template <bool F16>
__device__ __forceinline__ f32x4 mm16(short8 a, short8 b, f32x4 c) {
  if constexpr (F16)
    return __builtin_amdgcn_mfma_f32_16x16x32_f16(
        __builtin_bit_cast(half8, a), __builtin_bit_cast(half8, b), c, 0, 0, 0);
  else
    return __builtin_amdgcn_mfma_f32_16x16x32_bf16(a, b, c, 0, 0, 0);
}

// ---- merged prep: norm+f16 (x rows | anchor rows) + values^T --------------
__global__ __launch_bounds__(256) void prep_k(
    const float* __restrict__ x, const float* __restrict__ anc,
    const float* __restrict__ values, double* __restrict__ inv_norms,
    unsigned short* __restrict__ xh, unsigned short* __restrict__ ah,
    unsigned short* __restrict__ vbT) {
  const int blk = blockIdx.x;
  const int t = threadIdx.x;
  if (blk < B_ROWS + A_ROWS) {
    // ---- normprep branch (r3-proven f64 tree, fp-contract off) ----
#pragma clang fp contract(off)
    const bool isx = blk < B_ROWS;
    const int r = isx ? blk : blk - B_ROWS;
    const float* src = isx ? x + (size_t)r * D_DIM : anc + (size_t)r * D_DIM;
    double* inv_out = isx ? inv_norms + r : inv_norms + B_ROWS + r;
    unsigned short* dst = isx ? xh + (size_t)r * D_DIM : ah + (size_t)r * D_DIM;
    const float4 v = reinterpret_cast<const float4*>(src)[t];
    double s = (double)v.x * (double)v.x + (double)v.y * (double)v.y +
               (double)v.z * (double)v.z + (double)v.w * (double)v.w;
#pragma unroll
    for (int off = 32; off > 0; off >>= 1) s += __shfl_down(s, off);
    __shared__ double red[4];
    __shared__ double sinv;
    if ((t & 63) == 0) red[t >> 6] = s;
    __syncthreads();
    if (t == 0) {
      const double n = sqrt(red[0] + red[1] + red[2] + red[3]);
      const double inv = 1.0 / fmax(n, 1e-12);
      *inv_out = inv;
      sinv = inv;
    }
    __syncthreads();
    const float invn = (float)sinv;
    ushort4 o;
    o.x = f16_bits(v.x * invn); o.y = f16_bits(v.y * invn);
    o.z = f16_bits(v.z * invn); o.w = f16_bits(v.w * invn);
    reinterpret_cast<ushort4*>(dst)[t] = o;
  } else {
    // ---- prep_vt branch: 16x16 transpose tile ----
    const int tile = blk - (B_ROWS + A_ROWS);
    const int tx = t & 15, ty = t >> 4;
    __shared__ float sm[16][17];
    const int h0 = (tile & 63) * 16, a0 = (tile >> 6) * 16;
    sm[ty][tx] = values[(size_t)(a0 + ty) * H_DIM + h0 + tx];
    __syncthreads();
    vbT[(size_t)(h0 + ty) * A_ROWS + a0 + tx] = bf16_rne(sm[tx][ty]);
  }
}

// ------ 256x256 / BK=64 / 8-wave / 8-phase read-ahead GEMM core -----------
// LDS: buf0 {A:[256][64] @0, B @16384}, buf1 {A @32768, B @49152} (shorts).
// Chunk-XOR swizzle: row r's chunk k (16B) lives at slot k^(r&7); staging
// pre-swizzles the per-lane GLOBAL source so the LDS dest stays linear.
#define GBAR() do { __builtin_amdgcn_s_barrier(); \
                    asm volatile("" ::: "memory"); } while (0)
#define GVMC(n) asm volatile("s_waitcnt vmcnt(" #n ")" ::: "memory")

#define SCA(buf, c, kv) gload16(aS + (size_t)(c) * 64 * KDIM + (kv), \
                                (buf) + (c) * 4096 + tid * 8)
#define SCB(buf, c, kv) gload16(bS + (size_t)(c) * 64 * KDIM + (kv), \
                                (buf) + (c) * 4096 + tid * 8)

// frag reads: plain C++ short8 loads off precomputed swizzled bases;
// compiler inserts counted lgkmcnt and interleaves with MFMA.
#define LDX(pk0, pk1, mh) do { \
    _Pragma("unroll") for (int m_ = 0; m_ < 4; ++m_) { \
      Xf[0][m_] = *reinterpret_cast<const short8*>((pk0) + (mh) * 8192 + m_ * 1024); \
      Xf[1][m_] = *reinterpret_cast<const short8*>((pk1) + (mh) * 8192 + m_ * 1024); \
    } } while (0)

#define LDB(pk0, pk1, nh) do { \
    _Pragma("unroll") for (int n_ = 0; n_ < 2; ++n_) { \
      Bf[nh][0][n_] = *reinterpret_cast<const short8*>((pk0) + (nh) * 8192 + n_ * 1024); \
      Bf[nh][1][n_] = *reinterpret_cast<const short8*>((pk1) + (nh) * 8192 + n_ * 1024); \
    } } while (0)

#define MM4(mh, nh) do { \
    __builtin_amdgcn_s_setprio(1); \
    _Pragma("unroll") for (int ki_ = 0; ki_ < 2; ++ki_) \
    _Pragma("unroll") for (int m_ = 0; m_ < 4; ++m_) \
    _Pragma("unroll") for (int n_ = 0; n_ < 2; ++n_) \
      acc[(mh) * 4 + m_][(nh) * 2 + n_] = mm16<F16>( \
          Xf[ki_][m_], Bf[nh][ki_][n_], acc[(mh) * 4 + m_][(nh) * 2 + n_]); \
    __builtin_amdgcn_s_setprio(0); \
  } while (0)

template <int KDIM, bool F16>
__device__ __forceinline__ void gemm_core(
    const unsigned short* __restrict__ Amat, int m0,
    const unsigned short* __restrict__ Bmat, int n0,
    unsigned short* smem, f32x4 (&acc)[8][4], const int tid) {
  static_assert(KDIM % 128 == 0 && KDIM >= 256, "KDIM");
  const int lane = tid & 63, w = tid >> 6;
  const int wr = w >> 2, wc = w & 3;
  const int cl = lane & 15, kg = lane >> 4;
  unsigned short* const A0b = smem;
  unsigned short* const B0b = smem + 16384;
  unsigned short* const A1b = smem + 32768;
  unsigned short* const B1b = smem + 49152;
  // staging geometry: call c covers rows c*64 + (tid>>3), chunk slot tid&7;
  // source chunk = slot ^ (row&7); (c*64)&7==0 so the XOR is c-invariant.
  const int srow = tid >> 3;
  const int tcs = (tid & 7) ^ (srow & 7);
  const unsigned short* aS = Amat + (size_t)(m0 + srow) * KDIM + tcs * 8;
  const unsigned short* bS = Bmat + (size_t)(n0 + srow) * KDIM + tcs * 8;

  // frag-read swizzle constants: row&7 == cl&7 for all frag rows, so the
  // chunk index is lane-constant: cc = (ki*4+kg)^(cl&7); ki flips ^32 shorts.
  const int cc0 = kg ^ (cl & 7);
  const int oA0 = (wr * 64 + cl) * 64 + cc0 * 8;
  const int oA1 = oA0 ^ 32;
  const int oB0 = (wc * 32 + cl) * 64 + cc0 * 8;
  const int oB1 = oB0 ^ 32;
  const unsigned short* const pA0k0 = A0b + oA0;
  const unsigned short* const pA0k1 = A0b + oA1;
  const unsigned short* const pA1k0 = A1b + oA0;
  const unsigned short* const pA1k1 = A1b + oA1;
  const unsigned short* const pB0k0 = B0b + oB0;
  const unsigned short* const pB0k1 = B0b + oB1;
  const unsigned short* const pB1k0 = B1b + oB0;
  const unsigned short* const pB1k1 = B1b + oB1;

  short8 Xf[2][4], Bf[2][2][2];

  // prologue: t0 full (8) + t1 sans A-h1 (6) = 14 loads; wait all but t1's 6
  SCA(A0b, 0, 0); SCA(A0b, 1, 0);
  SCB(B0b, 0, 0); SCB(B0b, 1, 0);
  SCB(B0b, 2, 0); SCB(B0b, 3, 0);
  SCA(A0b, 2, 0); SCA(A0b, 3, 0);
  SCA(A1b, 0, 64); SCA(A1b, 1, 64);
  SCB(B1b, 0, 64); SCB(B1b, 1, 64);
  SCB(B1b, 2, 64); SCB(B1b, 3, 64);
  GVMC(6);
  GBAR();
  LDX(pA0k0, pA0k1, 0);  // X0(t0)
  LDB(pB0k0, pB0k1, 0);  // B0(t0)

  constexpr int G = KDIM / 128;  // groups of 2 K-tiles
#pragma unroll 1
  for (int g = 0; g < G - 1; ++g) {
    const int kA = g * 128 + 64;   // t1 = 2g+1 (buf1): A-h1 staged ph1
    const int kB = g * 128 + 128;  // t2 = 2g+2 (buf0): staged ph2-5
    const int kC = g * 128 + 192;  // t3 = 2g+3 (buf1): 3 halves, ph6-8
    // ph1: MM(0,0)=X0*B0; read B1 (for ph2)
    SCA(A1b, 2, kA); SCA(A1b, 3, kA);
    LDB(pB0k0, pB0k1, 1);
    MM4(0, 0);
    GBAR();
    // ph2: MM(0,1)=X0*B1; post-MM read X1 (SSA: MM reads old Xf)
    SCA(A0b, 0, kB); SCA(A0b, 1, kB);
    MM4(0, 1);
    LDX(pA0k0, pA0k1, 1);
    GBAR();
    // ph3: MM(1,0)=X1*B0
    SCB(B0b, 0, kB); SCB(B0b, 1, kB);
    MM4(1, 0);
    GBAR();
    // ph4: MM(1,1)=X1*B1 first; then vmc6+BAR (t1 resident all-waves);
    // then read X0',B0' (drain under ph5's MM issue).
    SCB(B0b, 2, kB); SCB(B0b, 3, kB);
    MM4(1, 1);
    GVMC(6);
    GBAR();
    LDX(pA1k0, pA1k1, 0);
    LDB(pB1k0, pB1k1, 0);
    GBAR();
    // ph5: MM(0,0)'=X0'*B0'; read B1'
    SCA(A0b, 2, kB); SCA(A0b, 3, kB);
    LDB(pB1k0, pB1k1, 1);
    MM4(0, 0);
    GBAR();
    // ph6: MM(0,1)'=X0'*B1'; post-MM read X1'
    SCA(A1b, 0, kC); SCA(A1b, 1, kC);
    MM4(0, 1);
    LDX(pA1k0, pA1k1, 1);
    GBAR();
    // ph7: MM(1,0)'=X1'*B0'
    SCB(B1b, 0, kC); SCB(B1b, 1, kC);
    MM4(1, 0);
    GBAR();
    // ph8: MM(1,1)'=X1'*B1' first; vmc6+BAR (t2 resident); read X0'',B0''
    SCB(B1b, 2, kC); SCB(B1b, 3, kC);
    MM4(1, 1);
    GVMC(6);
    GBAR();
    LDX(pA0k0, pA0k1, 0);
    LDB(pB0k0, pB0k1, 0);
    GBAR();
  }
  // tail group: t_{2G-2}(buf0), t_{2G-1}(buf1); only t_{2G-1} A-h1 to stage
  {
    const int kA = KDIM - 64;
    SCA(A1b, 2, kA); SCA(A1b, 3, kA);
    LDB(pB0k0, pB0k1, 1);
    MM4(0, 0);
    GBAR();
    MM4(0, 1);
    LDX(pA0k0, pA0k1, 1);
    GBAR();
    MM4(1, 0);
    GBAR();
    MM4(1, 1);
    GVMC(0);
    GBAR();
    LDX(pA1k0, pA1k1, 0);
    LDB(pB1k0, pB1k1, 0);
    GBAR();
    LDB(pB1k0, pB1k1, 1);
    MM4(0, 0);
    GBAR();
    MM4(0, 1);
    LDX(pA1k0, pA1k1, 1);
    GBAR();
    MM4(1, 0);
    GBAR();
    MM4(1, 1);
  }
}

// ---- GEMM1: f16 core + quantize/flag + IN-BLOCK fixup + single flush ------
__global__ __launch_bounds__(512, 2) void gemm1_k(
    const unsigned short* __restrict__ xh, const unsigned short* __restrict__ ah,
    const float* __restrict__ x, const float* __restrict__ anc,
    const double* __restrict__ inv_norms, unsigned short* __restrict__ kb2) {
  __shared__ __align__(128) unsigned short smem[65536];  // 128 KB
  __shared__ unsigned int lmeta[2048];

  const int tid = threadIdx.x, lane = tid & 63, w = tid >> 6;
  const int wr = w >> 2, wc = w & 3;
  const int cl = lane & 15, kg = lane >> 4;
  // XCD-bijective swizzle (m204; nwg=512, nwg%8==0, q=64)
  const int orig = blockIdx.y * 8 + blockIdx.x;
  const int swz = (orig & 7) * 64 + (orig >> 3);
  const int m0 = (swz >> 3) * 256, n0 = (swz & 7) * 256;

  f32x4 acc[8][4];
#pragma unroll
  for (int m = 0; m < 8; ++m)
#pragma unroll
    for (int n = 0; n < 4; ++n)
#pragma unroll
      for (int q = 0; q < 4; ++q) acc[m][n][q] = 0.0f;

  if (tid == 0) lmeta[0] = 0;  // published by core's prologue barrier

  gemm_core<D_DIM, true>(xh, m0, ah, n0, smem, acc, tid);

  // ---- epilogue A: quantize -> bf16 2k in LDS (XOR-swz) + local flags ----
  __syncthreads();
  unsigned short* sq = smem;  // [256][256] bf16, chunk-swizzled
#pragma unroll
  for (int mi = 0; mi < 8; ++mi)
#pragma unroll
    for (int ni = 0; ni < 4; ++ni) {
      const int rowb = (mi >> 2) * 128 + wr * 64 + (mi & 3) * 16 + kg * 4;
      const int col = (ni >> 1) * 128 + wc * 32 + (ni & 1) * 16 + cl;
#pragma unroll
      for (int reg = 0; reg < 4; ++reg) {
        const int row = rowb + reg;
        const float kr = acc[mi][ni][reg] * 20.0f;
        const float rr = rintf(kr);
        if (0.5f - fabsf(kr - rr) < 2e-3f) {  // r7-r28-validated window
          const unsigned int code = ((unsigned int)row << 8) | (unsigned int)col;
          const unsigned int li = atomicAdd(&lmeta[0], 1u);  // LDS atomic
          if (li < LCAP) lmeta[1 + li] = code;  // ~262 expected, 2040 cap
        }
        // swizzled store: chunk (col>>3) with low 3 bits XOR (row&7)
        const int ch = col >> 3;
        const int csw = (ch & 24) | ((ch & 7) ^ (row & 7));
        sq[row * 256 + csw * 8 + (col & 7)] =
            bf16_rne((float)(2 * (int)rr));  // exact
      }
    }
  __syncthreads();

  // ---- epilogue B: in-block fixup (waves split flag list, 2-deep pipe) ---
  {
    unsigned int cnt = lmeta[0];
    if (cnt > LCAP) cnt = LCAP;
    unsigned int i = (unsigned int)w;  // wave 0..7
    if (i < cnt) {
      unsigned int code = lmeta[1 + i];
      float4 xc0, xc1, xc2, xc3, ac0, ac1, ac2, ac3;
      {
        const int b = m0 + (int)(code >> 8), a = n0 + (int)(code & 255u);
        const float4* xp = reinterpret_cast<const float4*>(x + (size_t)b * D_DIM) + lane;
        const float4* ap = reinterpret_cast<const float4*>(anc + (size_t)a * D_DIM) + lane;
        xc0 = xp[0]; xc1 = xp[64]; xc2 = xp[128]; xc3 = xp[192];
        ac0 = ap[0]; ac1 = ap[64]; ac2 = ap[128]; ac3 = ap[192];
      }
      for (;;) {
        const unsigned int inext = i + 8;
        const bool have = inext < cnt;
        unsigned int coden = 0;
        float4 xn0, xn1, xn2, xn3, an0, an1, an2, an3;
        if (have) {  // issue next flag's gather (hides under current compute)
          coden = lmeta[1 + inext];
          const int b = m0 + (int)(coden >> 8), a = n0 + (int)(coden & 255u);
          const float4* xp = reinterpret_cast<const float4*>(x + (size_t)b * D_DIM) + lane;
          const float4* ap = reinterpret_cast<const float4*>(anc + (size_t)a * D_DIM) + lane;
          xn0 = xp[0]; xn1 = xp[64]; xn2 = xp[128]; xn3 = xp[192];
          an0 = ap[0]; an1 = ap[64]; an2 = ap[128]; an3 = ap[192];
        }
        {
          double p0 = (double)xc0.x * (double)ac0.x + (double)xc0.y * (double)ac0.y +
                      (double)xc0.z * (double)ac0.z + (double)xc0.w * (double)ac0.w;
          double p1 = (double)xc1.x * (double)ac1.x + (double)xc1.y * (double)ac1.y +
                      (double)xc1.z * (double)ac1.z + (double)xc1.w * (double)ac1.w;
          double p2 = (double)xc2.x * (double)ac2.x + (double)xc2.y * (double)ac2.y +
                      (double)xc2.z * (double)ac2.z + (double)xc2.w * (double)ac2.w;
          double p3 = (double)xc3.x * (double)ac3.x + (double)xc3.y * (double)ac3.y +
                      (double)xc3.z * (double)ac3.z + (double)xc3.w * (double)ac3.w;
          double s = (p0 + p1) + (p2 + p3);
          s += __shfl_xor(s, 32);
          s += __shfl_xor(s, 16);
          s += __shfl_xor(s, 8);
          s += __shfl_xor(s, 4);
          s += __shfl_xor(s, 2);
          s += __shfl_xor(s, 1);
          if (lane == 0) {
            const int lrow = (int)(code >> 8), lcol = (int)(code & 255u);
            const int b = m0 + lrow, a = n0 + lcol;
            const double sim = s * inv_norms[b] * inv_norms[B_ROWS + a];
            const double kr = sim / 0.05;
            const double r = rint(kr);
            const double fr = kr - r;
            int k2 = 2 * (int)r;
            if (0.5 - fabs(fr) < 2.5e-6) k2 += (fr > 0.0) ? 1 : -1;  // hedge
            const int ch = lcol >> 3;
            const int csw = (ch & 24) | ((ch & 7) ^ (lrow & 7));
            sq[lrow * 256 + csw * 8 + (lcol & 7)] = bf16_rne((float)k2);
          }
        }
        if (!have) break;
        i = inext; code = coden;
        xc0 = xn0; xc1 = xn1; xc2 = xn2; xc3 = xn3;
        ac0 = an0; ac1 = an1; ac2 = an2; ac3 = an3;
      }
    }
  }
  __syncthreads();

  // ---- epilogue C: single coalesced flush sq -> kb2 ----------------------
  {
    const int row = tid >> 1, half = tid & 1;
    unsigned short* dst = kb2 + (size_t)(m0 + row) * A_ROWS + n0 + half * 128;
#pragma unroll
    for (int j = 0; j < 16; ++j) {
      const int creal = half * 16 + j;
      const int csw = (creal & 24) | ((creal & 7) ^ (row & 7));
      reinterpret_cast<int4*>(dst)[j] =
          *reinterpret_cast<const int4*>(sq + row * 256 + csw * 8);
    }
  }
}

// ---- GEMM2: bf16 chain, K=2048, 256^2 8-phase core, out = .025*k2@vbT -----
__global__ __launch_bounds__(512, 2) void gemm2_k(
    const unsigned short* __restrict__ kb2, const unsigned short* __restrict__ vbT,
    float* __restrict__ out) {
  __shared__ __align__(128) unsigned short smem[65536];  // 128 KB

  const int tid = threadIdx.x, lane = tid & 63, w = tid >> 6;
  const int wr = w >> 2, wc = w & 3;
  const int cl = lane & 15, kg = lane >> 4;
  // XCD-bijective swizzle (nwg=256, q=32)
  const int orig = blockIdx.y * 4 + blockIdx.x;
  const int swz = (orig & 7) * 32 + (orig >> 3);
  const int m0 = (swz >> 2) * 256, h0 = (swz & 3) * 256;

  f32x4 acc[8][4];
#pragma unroll
  for (int m = 0; m < 8; ++m)
#pragma unroll
    for (int n = 0; n < 4; ++n)
#pragma unroll
      for (int q = 0; q < 4; ++q) acc[m][n][q] = 0.0f;

  gemm_core<A_ROWS, false>(kb2, m0, vbT, h0, smem, acc, tid);

#pragma unroll
  for (int mi = 0; mi < 8; ++mi)
#pragma unroll
    for (int ni = 0; ni < 4; ++ni) {
      const int rowb = (mi >> 2) * 128 + wr * 64 + (mi & 3) * 16 + kg * 4;
      const int col = (ni >> 1) * 128 + wc * 32 + (ni & 1) * 16 + cl;
#pragma unroll
      for (int reg = 0; reg < 4; ++reg)
        out[(size_t)(m0 + rowb + reg) * H_DIM + h0 + col] =
            0.025f * acc[mi][ni][reg];
    }
}

// ---------------------------------------------------------------------------
extern "C" void kernel_launch(void* const* d_in, const int* in_sizes, int n_in,
                              void* d_out, int out_size, void* d_ws, size_t ws_size,
                              hipStream_t stream) {
  const float* x      = (const float*)d_in[0];
  const float* anc    = (const float*)d_in[1];
  const float* values = (const float*)d_in[2];
  float* out = (float*)d_out;

  char* ws = (char*)d_ws;
  double* inv_norms    = (double*)(ws);
  unsigned short* xh   = (unsigned short*)(ws + 0x324000);
  unsigned short* ah   = (unsigned short*)(ws + 0x2324000);
  unsigned short* vbT  = (unsigned short*)(ws + 0x2724000);
  unsigned short* kb2  = (unsigned short*)(ws + 0x2B24000);

  prep_k<<<B_ROWS + A_ROWS + (H_DIM / 16) * (A_ROWS / 16), 256, 0, stream>>>(
      x, anc, values, inv_norms, xh, ah, vbT);
  gemm1_k<<<dim3(A_ROWS / 256, B_ROWS / 256), 512, 0, stream>>>(
      xh, ah, x, anc, inv_norms, kb2);
  gemm2_k<<<dim3(H_DIM / 256, B_ROWS / 256), 512, 0, stream>>>(kb2, vbT, out);
}